// Round 4
// baseline (11511.101 us; speedup 1.0000x reference)
//
#include <hip/hip_runtime.h>
#include <math.h>

// ---------------- problem constants ----------------
#define Bb   128
#define Hd   1024
#define Ld   256
#define Cd   20
#define Nd   30
#define Md   3

using bfrag = __attribute__((ext_vector_type(8)))  short;  // 8 bf16 (4 VGPRs)
using f16v  = __attribute__((ext_vector_type(16))) float;  // 32x32 C/D

union Pack8 { bfrag v; unsigned short u[8]; };

__device__ __forceinline__ float sigm(float x) { return 1.0f / (1.0f + expf(-x)); }

__device__ __forceinline__ unsigned short bf_rne(float x) {
    unsigned u = __float_as_uint(x);
    unsigned r = (u + 0x7fffu + ((u >> 16) & 1u)) >> 16;
    return (unsigned short)r;
}
__device__ __forceinline__ float bf_f(unsigned short h) {
    return __uint_as_float(((unsigned)h) << 16);
}

#define MFMA(a,b,c) __builtin_amdgcn_mfma_f32_32x32x16_bf16((a),(b),(c),0,0,0)

// async global->LDS, 16B/lane; aux=0 plain (weights, L2-cacheable)
__device__ __forceinline__ void gld_lds16(const void* g, void* s) {
    __builtin_amdgcn_global_load_lds((const __attribute__((address_space(1))) void*)g,
                                     (__attribute__((address_space(3))) void*)s, 16, 0, 0);
}
// aux=16 (SC1): agent-coherent load — bypass possibly-stale per-XCD L2 (activations)
__device__ __forceinline__ void gld_lds16c(const void* g, void* s) {
    __builtin_amdgcn_global_load_lds((const __attribute__((address_space(1))) void*)g,
                                     (__attribute__((address_space(3))) void*)s, 16, 0, 16);
}
// s_waitcnt imm: vmcnt[3:0] | expcnt<<4 (7=nowait) | lgkmcnt<<8 (15=nowait)
#define WAIT_VM(n) __builtin_amdgcn_s_waitcnt(0x0F70 | (n))
#define BARRIER()  __builtin_amdgcn_s_barrier()

// ---------------- preamble kernels ----------------
__global__ void cast_kernel(const float* __restrict__ src,
                            unsigned short* __restrict__ dst, int n)
{
    for (int i = blockIdx.x * blockDim.x + threadIdx.x; i < n; i += gridDim.x * blockDim.x)
        dst[i] = bf_rne(src[i]);
}

__global__ void cast_pad_kernel(const float* __restrict__ src,
                                unsigned short* __restrict__ dst,
                                int rows, int K, int Kp)
{
    int n = rows * Kp;
    for (int i = blockIdx.x * blockDim.x + threadIdx.x; i < n; i += gridDim.x * blockDim.x) {
        int r = i / Kp, k = i - r * Kp;
        dst[i] = bf_rne((k < K) ? src[r * K + k] : 0.0f);
    }
}

__global__ void split_kernel(const float* __restrict__ src,
                             unsigned short* __restrict__ hi,
                             unsigned short* __restrict__ lo, int n)
{
    for (int i = blockIdx.x * blockDim.x + threadIdx.x; i < n; i += gridDim.x * blockDim.x) {
        float x = src[i];
        unsigned short h = bf_rne(x);
        hi[i] = h;
        lo[i] = bf_rne(x - bf_f(h));
    }
}

// ---------------- persistent fused LSTM kernel ----------------
// grid 256 x 512. 1 WG/CU (128KB LDS) -> all WGs co-resident. Steps 1..255:
//   phase A: gates1 = h1[prv] @ Whh1 (8 chunks) + cat(cond,out[t-1]) @ Wih1;
//            elementwise + dropout -> h1[cur] (bf16 hi/lo, agent-scope stores)
//   grid barrier
//   phase B: gates2 = h1[cur] @ Wih2 + h2[prv] @ Whh2 (16 chunks);
//            elementwise -> h2[cur]; FC atomics into out[t]
//   grid barrier
// Staging: 4 LDS buffers, 3 chunks in flight (WAIT_VM(12)), k8-block XOR swizzle.
// h buffers rotate over 4 parities (stale-L2 defense); c1/c2 are CU-local.
__global__ __launch_bounds__(512, 1) void lstm_persistent(
    const unsigned short* __restrict__ W1, const unsigned short* __restrict__ W2,
    const unsigned short* __restrict__ W3, const unsigned short* __restrict__ Wsm,
    const float* __restrict__ cond, const float* __restrict__ dmask,
    const float* __restrict__ bih1, const float* __restrict__ bhh1,
    const float* __restrict__ bih2, const float* __restrict__ bhh2,
    float* __restrict__ c1, float* __restrict__ c2,
    unsigned short* __restrict__ h1h, unsigned short* __restrict__ h1l,
    unsigned short* __restrict__ h2h, unsigned short* __restrict__ h2l,
    const float* __restrict__ Wfc, const float* __restrict__ bfc,
    float* __restrict__ out, unsigned* __restrict__ barcnt)
{
    __shared__ union {
        struct { unsigned short A[4][2][4096]; unsigned short W[4][8192]; } s;  // 128 KB
        struct { float part[8][32][65]; float hbuf[32][16]; } r;                // aliases s
    } U;

    const int bid   = blockIdx.x;
    const int mtile = (bid >> 3) & 3;
    const int jtile = (bid & 7) * 8 + (bid >> 5);   // XCD-swizzled
    const int j0 = jtile * 16, m0 = mtile * 32;

    const int tid  = threadIdx.x;
    const int wave = tid >> 6;
    const int lane = tid & 63;
    const int ml   = lane & 31;
    const int q    = lane >> 5;
    const size_t S = (size_t)Bb * Hd;

    // A staging slot: thread -> (row am, dest k8-pos abp, source k8-block abs_)
    const int am = tid >> 4, abp = tid & 15, abs_ = abp ^ (am & 15);
    const size_t aoff_base = (size_t)(m0 + am) * Hd + abs_ * 8;

    unsigned bar_target = 0;

    auto grid_bar = [&]() {
        bar_target += 256;
        __syncthreads();   // drains vmcnt -> all scoped stores visible before arrival
        if (tid == 0) {
            __hip_atomic_fetch_add(barcnt, 1u, __ATOMIC_RELAXED, __HIP_MEMORY_SCOPE_AGENT);
            while (__hip_atomic_load(barcnt, __ATOMIC_RELAXED, __HIP_MEMORY_SCOPE_AGENT) < bar_target)
                __builtin_amdgcn_s_sleep(2);
        }
        __syncthreads();
    };

    auto stageA = [&](const unsigned short* Ah, const unsigned short* Al, int cb, int buf) {
        const size_t goff = aoff_base + cb;
        gld_lds16c(Ah + goff, &U.s.A[buf][0][wave * 512]);
        gld_lds16c(Al + goff, &U.s.A[buf][1][wave * 512]);
    };
    auto stageW = [&](const unsigned short* Wg, int cb, int buf) {
        #pragma unroll
        for (int r = 0; r < 2; ++r) {
            const int f = r * 512 + tid;
            const int n = f >> 4, bp = f & 15, bs = bp ^ (n & 15);
            const size_t goff = (size_t)((n >> 4) * Hd + j0 + (n & 15)) * Hd + cb + bs * 8;
            gld_lds16(Wg + goff, &U.s.W[buf][r * 4096 + wave * 512]);
        }
    };
    auto computeC = [&](int buf, f16v& C0, f16v& C1) {
        const int b = 2 * wave + q;
        const int soff = (b ^ (ml & 15)) << 3;
        bfrag ah  = *(const bfrag*)&U.s.A[buf][0][ml * 128 + soff];
        bfrag al  = *(const bfrag*)&U.s.A[buf][1][ml * 128 + soff];
        bfrag w0f = *(const bfrag*)&U.s.W[buf][ml * 128 + soff];
        bfrag w1f = *(const bfrag*)&U.s.W[buf][(ml + 32) * 128 + soff];
        C0 = MFMA(ah, w0f, C0);
        C1 = MFMA(ah, w1f, C1);
        C0 = MFMA(al, w0f, C0);
        C1 = MFMA(al, w1f, C1);
    };
    auto dump_part = [&](const f16v& C0, const f16v& C1) {
        #pragma unroll
        for (int r = 0; r < 16; ++r) {
            const int mrow = (r & 3) + 8 * (r >> 2) + 4 * q;
            U.r.part[wave][mrow][ml]      = C0[r];
            U.r.part[wave][mrow][32 + ml] = C1[r];
        }
    };

    const int g0 = ml >> 4, jj0 = ml & 15;
    const size_t row0 = (size_t)(g0 * Hd + j0 + jj0);
    const size_t row1 = (size_t)((g0 + 2) * Hd + j0 + jj0);

    #pragma clang loop unroll(disable)
    for (int t = 1; t < Ld; ++t) {
        const int cur = t & 3, prv = (t - 1) & 3;
        float* outp_t = out + (size_t)t * Bb * Md;
        const float* outp_p = out + (size_t)(t - 1) * Bb * Md;

        // ================= phase A : cell1 =================
        {
            const unsigned short* Ah = h1h + (size_t)prv * S;
            const unsigned short* Al = h1l + (size_t)prv * S;
            stageA(Ah, Al, 0, 0);   stageW(W1, 0, 0);
            stageA(Ah, Al, 128, 1); stageW(W1, 128, 1);
            stageA(Ah, Al, 256, 2); stageW(W1, 256, 2);
            if (bid == 0) {
                for (int i = tid; i < Bb * Md; i += 512)
                    __hip_atomic_store(&outp_t[i], bfc[i % Md], __ATOMIC_RELAXED, __HIP_MEMORY_SCOPE_AGENT);
            }
            f16v C0, C1;
            #pragma unroll
            for (int r = 0; r < 16; ++r) { C0[r] = 0.f; C1[r] = 0.f; }
            for (int c = 0; c < 8; ++c) {
                const int p = c & 3;
                if (c + 3 < 8) { stageA(Ah, Al, (c + 3) * 128, (c + 3) & 3); stageW(W1, (c + 3) * 128, (c + 3) & 3); }
                if (c + 3 < 8) WAIT_VM(12);
                else if (c + 2 < 8) WAIT_VM(8);
                else if (c + 1 < 8) WAIT_VM(4);
                else WAIT_VM(0);
                BARRIER();
                computeC(p, C0, C1);
                BARRIER();
            }
            // small segment (wave 0): cat(cond[t][20], out[t-1][3]) padded to K=32
            if (wave == 0) {
                const float* crow = cond + (size_t)t * Bb * Cd + (m0 + ml) * Cd;
                const float* orow = outp_p + (m0 + ml) * Md;
                float xv[2][8];
                #pragma unroll
                for (int j = 0; j < 8; ++j) { xv[0][j] = 0.f; xv[1][j] = 0.f; }
                if (q == 0) {
                    #pragma unroll
                    for (int j = 0; j < 8; ++j) xv[0][j] = crow[j];
                    xv[1][0] = crow[16]; xv[1][1] = crow[17];
                    xv[1][2] = crow[18]; xv[1][3] = crow[19];
                    xv[1][4] = __hip_atomic_load((float*)&orow[0], __ATOMIC_RELAXED, __HIP_MEMORY_SCOPE_AGENT);
                    xv[1][5] = __hip_atomic_load((float*)&orow[1], __ATOMIC_RELAXED, __HIP_MEMORY_SCOPE_AGENT);
                    xv[1][6] = __hip_atomic_load((float*)&orow[2], __ATOMIC_RELAXED, __HIP_MEMORY_SCOPE_AGENT);
                } else {
                    #pragma unroll
                    for (int j = 0; j < 8; ++j) xv[0][j] = crow[8 + j];
                }
                #pragma unroll
                for (int ch = 0; ch < 2; ++ch) {
                    Pack8 ah, al;
                    #pragma unroll
                    for (int j = 0; j < 8; ++j) {
                        unsigned short h = bf_rne(xv[ch][j]);
                        ah.u[j] = h;
                        al.u[j] = bf_rne(xv[ch][j] - bf_f(h));
                    }
                    const int kk = ch * 16 + 8 * q;
                    bfrag b0 = *(const bfrag*)(Wsm + row0 * 32 + kk);
                    bfrag b1 = *(const bfrag*)(Wsm + row1 * 32 + kk);
                    C0 = MFMA(ah.v, b0, C0);
                    C1 = MFMA(ah.v, b1, C1);
                    C0 = MFMA(al.v, b0, C0);
                    C1 = MFMA(al.v, b1, C1);
                }
            }
            dump_part(C0, C1);
            __syncthreads();
            if (tid < 256) {
                const int m = tid >> 3, j2 = (tid & 7) * 2;
                const int b = m0 + m, jc = j0 + j2;
                const size_t idx = (size_t)b * Hd + jc;
                float g[4][2];
                #pragma unroll
                for (int gg = 0; gg < 4; ++gg) {
                    #pragma unroll
                    for (int e = 0; e < 2; ++e) {
                        float s = 0.f;
                        #pragma unroll
                        for (int w = 0; w < 8; ++w) s += U.r.part[w][m][gg * 16 + j2 + e];
                        const int n = gg * Hd + jc + e;
                        g[gg][e] = s + bih1[n] + bhh1[n];
                    }
                }
                float2 cp = *(const float2*)&c1[idx];
                float2 mv = *(const float2*)&dmask[(size_t)t * S + idx];
                float cn0 = sigm(g[1][0]) * cp.x + sigm(g[0][0]) * tanhf(g[2][0]);
                float cn1 = sigm(g[1][1]) * cp.y + sigm(g[0][1]) * tanhf(g[2][1]);
                float hv0 = sigm(g[3][0]) * tanhf(cn0) * mv.x;
                float hv1 = sigm(g[3][1]) * tanhf(cn1) * mv.y;
                *(float2*)&c1[idx] = make_float2(cn0, cn1);
                unsigned short h0 = bf_rne(hv0), h1_ = bf_rne(hv1);
                unsigned hp = (unsigned)h0 | ((unsigned)h1_ << 16);
                unsigned lp = (unsigned)bf_rne(hv0 - bf_f(h0)) | ((unsigned)bf_rne(hv1 - bf_f(h1_)) << 16);
                __hip_atomic_store((unsigned*)&h1h[(size_t)cur * S + idx], hp, __ATOMIC_RELAXED, __HIP_MEMORY_SCOPE_AGENT);
                __hip_atomic_store((unsigned*)&h1l[(size_t)cur * S + idx], lp, __ATOMIC_RELAXED, __HIP_MEMORY_SCOPE_AGENT);
            }
        }
        grid_bar();

        // ================= phase B : cell2 =================
        {
            const unsigned short* A2h = h1h + (size_t)cur * S;
            const unsigned short* A2l = h1l + (size_t)cur * S;
            const unsigned short* A3h = h2h + (size_t)prv * S;
            const unsigned short* A3l = h2l + (size_t)prv * S;
            auto stageB = [&](int c, int buf) {
                if (c < 8) { stageA(A2h, A2l, c * 128, buf); stageW(W2, c * 128, buf); }
                else       { stageA(A3h, A3l, (c - 8) * 128, buf); stageW(W3, (c - 8) * 128, buf); }
            };
            stageB(0, 0); stageB(1, 1); stageB(2, 2);
            f16v C0, C1;
            #pragma unroll
            for (int r = 0; r < 16; ++r) { C0[r] = 0.f; C1[r] = 0.f; }
            for (int c = 0; c < 16; ++c) {
                const int p = c & 3;
                if (c + 3 < 16) stageB(c + 3, (c + 3) & 3);
                if (c + 3 < 16) WAIT_VM(12);
                else if (c + 2 < 16) WAIT_VM(8);
                else if (c + 1 < 16) WAIT_VM(4);
                else WAIT_VM(0);
                BARRIER();
                computeC(p, C0, C1);
                BARRIER();
            }
            dump_part(C0, C1);
            __syncthreads();
            if (tid < 256) {
                const int m = tid >> 3, j2 = (tid & 7) * 2;
                const int b = m0 + m, jc = j0 + j2;
                const size_t idx = (size_t)b * Hd + jc;
                float g[4][2];
                #pragma unroll
                for (int gg = 0; gg < 4; ++gg) {
                    #pragma unroll
                    for (int e = 0; e < 2; ++e) {
                        float s = 0.f;
                        #pragma unroll
                        for (int w = 0; w < 8; ++w) s += U.r.part[w][m][gg * 16 + j2 + e];
                        const int n = gg * Hd + jc + e;
                        g[gg][e] = s + bih2[n] + bhh2[n];
                    }
                }
                float2 cp = *(const float2*)&c2[idx];
                float cn0 = sigm(g[1][0]) * cp.x + sigm(g[0][0]) * tanhf(g[2][0]);
                float cn1 = sigm(g[1][1]) * cp.y + sigm(g[0][1]) * tanhf(g[2][1]);
                float hv0 = sigm(g[3][0]) * tanhf(cn0);
                float hv1 = sigm(g[3][1]) * tanhf(cn1);
                *(float2*)&c2[idx] = make_float2(cn0, cn1);
                U.r.hbuf[m][j2]     = hv0;
                U.r.hbuf[m][j2 + 1] = hv1;
                unsigned short h0 = bf_rne(hv0), h1_ = bf_rne(hv1);
                unsigned hp = (unsigned)h0 | ((unsigned)h1_ << 16);
                unsigned lp = (unsigned)bf_rne(hv0 - bf_f(h0)) | ((unsigned)bf_rne(hv1 - bf_f(h1_)) << 16);
                __hip_atomic_store((unsigned*)&h2h[(size_t)cur * S + idx], hp, __ATOMIC_RELAXED, __HIP_MEMORY_SCOPE_AGENT);
                __hip_atomic_store((unsigned*)&h2l[(size_t)cur * S + idx], lp, __ATOMIC_RELAXED, __HIP_MEMORY_SCOPE_AGENT);
            }
            __syncthreads();
            if (tid < 32) {
                const int b = m0 + tid;
                #pragma unroll
                for (int mm = 0; mm < Md; ++mm) {
                    float s = 0.0f;
                    #pragma unroll
                    for (int jj = 0; jj < 16; ++jj) s += U.r.hbuf[tid][jj] * Wfc[mm * Hd + j0 + jj];
                    atomicAdd(&outp_t[b * Md + mm], s);
                }
            }
        }
        grid_bar();
    }
}

// ---------------- R0 fp32 VALU cell kernel (step 0 + ws fallback) ----------------
#define BT   64
#define JT   8
#define RT   32
#define KC   64
#define NT   256
#define NCHUNK 16
#define XSs  68
#define SMs  52
#define GBs  33

__global__ __launch_bounds__(NT) void lstm_cell_kernel(
    const float* __restrict__ Xbig0, const float* __restrict__ Wbig0,
    const float* __restrict__ Xbig1, const float* __restrict__ Wbig1,
    const float* __restrict__ Xsm0p, int K0,
    const float* __restrict__ Xsm1p, int K1,
    const float* __restrict__ Wsmall,
    const float* __restrict__ bih, const float* __restrict__ bhh,
    const float* __restrict__ cprev, float* __restrict__ cnew,
    const float* __restrict__ mask,
    float* __restrict__ hnew,
    const float* __restrict__ Wfc, const float* __restrict__ bfc,
    float* __restrict__ outp, int initOut)
{
    __shared__ float Xs[BT][XSs];
    __shared__ float Ws[RT][XSs];
    __shared__ float gbuf[BT][GBs];
    __shared__ float hbuf[BT][JT];
    __shared__ float Xsm[BT][SMs];
    __shared__ float Wsm[RT][SMs];

    const int tid = threadIdx.x;
    const int j0  = blockIdx.x * JT;
    const int b0  = blockIdx.y * BT;
    const int jp  = tid & 15;
    const int bq  = tid >> 4;

    auto GROW = [&](int r) { return ((r >> 3) * Hd + j0 + (r & 7)); };

    float acc[4][2];
    #pragma unroll
    for (int i = 0; i < 4; ++i) { acc[i][0] = 0.f; acc[i][1] = 0.f; }

    if (initOut && blockIdx.x == 0 && blockIdx.y == 0) {
        for (int i = tid; i < Bb * 3; i += NT) outp[i] = bfc[i % 3];
    }

    for (int seg = 0; seg < 2; ++seg) {
        const float* __restrict__ Xg = (seg == 0) ? Xbig0 : Xbig1;
        const float* __restrict__ Wg = (seg == 0) ? Wbig0 : Wbig1;
        if (Xg == nullptr) continue;

        float4 xr[4], wr[2];
        #pragma unroll
        for (int p = 0; p < 4; ++p) {
            int fi = p * NT + tid; int bloc = fi >> 4; int kq = fi & 15;
            xr[p] = *(const float4*)(Xg + (size_t)(b0 + bloc) * Hd + kq * 4);
        }
        #pragma unroll
        for (int p = 0; p < 2; ++p) {
            int fi = p * NT + tid; int r = fi >> 4; int kq = fi & 15;
            wr[p] = *(const float4*)(Wg + (size_t)GROW(r) * Hd + kq * 4);
        }
        #pragma unroll
        for (int p = 0; p < 4; ++p) { int fi = p * NT + tid; *(float4*)&Xs[fi >> 4][(fi & 15) * 4] = xr[p]; }
        #pragma unroll
        for (int p = 0; p < 2; ++p) { int fi = p * NT + tid; *(float4*)&Ws[fi >> 4][(fi & 15) * 4] = wr[p]; }
        __syncthreads();

        for (int kc = 0; kc < NCHUNK; ++kc) {
            const bool more = (kc + 1) < NCHUNK;
            if (more) {
                const int k0n = (kc + 1) * KC;
                #pragma unroll
                for (int p = 0; p < 4; ++p) {
                    int fi = p * NT + tid; int bloc = fi >> 4; int kq = fi & 15;
                    xr[p] = *(const float4*)(Xg + (size_t)(b0 + bloc) * Hd + k0n + kq * 4);
                }
                #pragma unroll
                for (int p = 0; p < 2; ++p) {
                    int fi = p * NT + tid; int r = fi >> 4; int kq = fi & 15;
                    wr[p] = *(const float4*)(Wg + (size_t)GROW(r) * Hd + k0n + kq * 4);
                }
            }
            #pragma unroll 4
            for (int kk = 0; kk < KC; kk += 4) {
                float4 w0 = *(const float4*)&Ws[jp][kk];
                float4 w1 = *(const float4*)&Ws[jp + 16][kk];
                #pragma unroll
                for (int bb = 0; bb < 4; ++bb) {
                    float4 xvv = *(const float4*)&Xs[bq + 16 * bb][kk];
                    acc[bb][0] += xvv.x * w0.x + xvv.y * w0.y + xvv.z * w0.z + xvv.w * w0.w;
                    acc[bb][1] += xvv.x * w1.x + xvv.y * w1.y + xvv.z * w1.z + xvv.w * w1.w;
                }
            }
            __syncthreads();
            if (more) {
                #pragma unroll
                for (int p = 0; p < 4; ++p) { int fi = p * NT + tid; *(float4*)&Xs[fi >> 4][(fi & 15) * 4] = xr[p]; }
                #pragma unroll
                for (int p = 0; p < 2; ++p) { int fi = p * NT + tid; *(float4*)&Ws[fi >> 4][(fi & 15) * 4] = wr[p]; }
                __syncthreads();
            }
        }
    }

    if (Wsmall) {
        const int Kt = K0 + K1;
        for (int i = tid; i < BT * Kt; i += NT) {
            int bloc = i / Kt, k = i % Kt;
            Xsm[bloc][k] = (k < K0) ? Xsm0p[(size_t)(b0 + bloc) * K0 + k]
                                    : Xsm1p[(size_t)(b0 + bloc) * K1 + (k - K0)];
        }
        for (int i = tid; i < RT * Kt; i += NT) {
            int r = i / Kt, k = i % Kt;
            Wsm[r][k] = Wsmall[(size_t)GROW(r) * Kt + k];
        }
        __syncthreads();
        for (int k = 0; k < Kt; ++k) {
            float w0 = Wsm[jp][k], w1 = Wsm[jp + 16][k];
            #pragma unroll
            for (int bb = 0; bb < 4; ++bb) {
                float xvv = Xsm[bq + 16 * bb][k];
                acc[bb][0] += xvv * w0;
                acc[bb][1] += xvv * w1;
            }
        }
    }

    __syncthreads();
    #pragma unroll
    for (int bb = 0; bb < 4; ++bb) {
        gbuf[bq + 16 * bb][jp]      = acc[bb][0];
        gbuf[bq + 16 * bb][jp + 16] = acc[bb][1];
    }
    __syncthreads();

    for (int p = tid; p < BT * JT; p += NT) {
        int bloc = p & (BT - 1);
        int j    = p >> 6;
        int bg   = b0 + bloc;
        int jc   = j0 + j;
        float gi = gbuf[bloc][j]      + bih[jc]          + bhh[jc];
        float gf = gbuf[bloc][8 + j]  + bih[Hd + jc]     + bhh[Hd + jc];
        float gg = gbuf[bloc][16 + j] + bih[2 * Hd + jc] + bhh[2 * Hd + jc];
        float go = gbuf[bloc][24 + j] + bih[3 * Hd + jc] + bhh[3 * Hd + jc];
        float cp = cprev[(size_t)bg * Hd + jc];
        float cn = sigm(gf) * cp + sigm(gi) * tanhf(gg);
        float hv = sigm(go) * tanhf(cn);
        if (mask) hv *= mask[(size_t)bg * Hd + jc];
        cnew[(size_t)bg * Hd + jc] = cn;
        hnew[(size_t)bg * Hd + jc] = hv;
        hbuf[bloc][j] = hv;
    }

    if (Wfc) {
        __syncthreads();
        if (tid < BT) {
            int bg = b0 + tid;
            #pragma unroll
            for (int m = 0; m < 3; ++m) {
                float s = 0.f;
                #pragma unroll
                for (int j = 0; j < JT; ++j) s += hbuf[tid][j] * Wfc[m * Hd + j0 + j];
                atomicAdd(&outp[bg * 3 + m], s);
            }
        }
    }
}

// ---------------- launch ----------------
extern "C" void kernel_launch(void* const* d_in, const int* in_sizes, int n_in,
                              void* d_out, int out_size, void* d_ws, size_t ws_size,
                              hipStream_t stream)
{
    (void)in_sizes; (void)n_in; (void)out_size;
    const float* cond   = (const float*)d_in[0];
    const float* noise  = (const float*)d_in[1];
    const float* h_init = (const float*)d_in[2];
    const float* c_init = (const float*)d_in[3];
    const float* dmask  = (const float*)d_in[4];
    const float* Wih0   = (const float*)d_in[5];
    const float* Whh0   = (const float*)d_in[6];
    const float* bih0   = (const float*)d_in[7];
    const float* bhh0   = (const float*)d_in[8];
    const float* Wih1   = (const float*)d_in[9];
    const float* Whh1   = (const float*)d_in[10];
    const float* bih1   = (const float*)d_in[11];
    const float* bhh1   = (const float*)d_in[12];
    const float* Wih2   = (const float*)d_in[13];
    const float* Whh2   = (const float*)d_in[14];
    const float* bih2   = (const float*)d_in[15];
    const float* bhh2   = (const float*)d_in[16];
    const float* Wfc    = (const float*)d_in[17];
    const float* bfc    = (const float*)d_in[18];
    float* out = (float*)d_out;

    char* wsb = (char*)d_ws;
    size_t off = 0;
    auto alloc = [&](size_t bytes) { size_t o = off; off += (bytes + 255) & ~(size_t)255; return o; };

    const size_t WBIG = (size_t)4 * Hd * Hd * 2;     // 4096x1024 bf16
    const size_t S    = (size_t)Bb * Hd;
    const size_t HB4  = S * 2 * 4;                   // bf16 h buffer, 4 parities
    const size_t HF   = S * 4;                       // fp32

    size_t o_w1 = alloc(WBIG);                        // Whh1 bf16
    size_t o_w2 = alloc(WBIG);                        // Wih2 bf16
    size_t o_w3 = alloc(WBIG);                        // Whh2 bf16
    size_t o_wsm = alloc((size_t)4 * Hd * 32 * 2);    // Wih1 padded bf16
    size_t o_h1h = alloc(HB4), o_h1l = alloc(HB4);
    size_t o_h2h = alloc(HB4), o_h2l = alloc(HB4);
    size_t o_c1 = alloc(HF), o_c2 = alloc(HF);
    size_t o_f1 = alloc(HF), o_f2 = alloc(HF);
    off = (off + 4095) & ~(size_t)4095;
    size_t o_bar = alloc(4096);
    const size_t needed = off;

    if (ws_size < needed) {
        // -------- fallback: full R0 fp32 path --------
        float* ws = (float*)d_ws;
        float* h1a = ws;         float* h1b = ws + S;
        float* h2a = ws + 2 * S; float* h2b = ws + 3 * S;
        float* c1  = ws + 4 * S; float* c2  = ws + 5 * S;
        dim3 grid(Hd / JT, Bb / BT);
        dim3 blk(NT);
        lstm_cell_kernel<<<grid, blk, 0, stream>>>(
            h_init, Whh0, nullptr, nullptr, cond, Cd, noise, Nd, Wih0,
            bih0, bhh0, c_init, c1, dmask, h1a, nullptr, bfc, out, 1);
        lstm_cell_kernel<<<grid, blk, 0, stream>>>(
            h1a, Wih2, h_init, Whh2, nullptr, 0, nullptr, 0, nullptr,
            bih2, bhh2, c_init, c2, nullptr, h2a, Wfc, bfc, out, 0);
        const float* h1prev = h1a; const float* h2prev = h2a;
        for (int t = 1; t < Ld; ++t) {
            float* h1cur = (t & 1) ? h1b : h1a;
            float* h2cur = (t & 1) ? h2b : h2a;
            lstm_cell_kernel<<<grid, blk, 0, stream>>>(
                h1prev, Whh1, nullptr, nullptr,
                cond + (size_t)t * Bb * Cd, Cd, out + (size_t)(t - 1) * Bb * Md, Md, Wih1,
                bih1, bhh1, c1, c1, dmask + (size_t)t * Bb * Hd, h1cur,
                nullptr, bfc, out + (size_t)t * Bb * Md, 1);
            lstm_cell_kernel<<<grid, blk, 0, stream>>>(
                h1cur, Wih2, h2prev, Whh2, nullptr, 0, nullptr, 0, nullptr,
                bih2, bhh2, c2, c2, nullptr, h2cur, Wfc, bfc, out + (size_t)t * Bb * Md, 0);
            h1prev = h1cur; h2prev = h2cur;
        }
        return;
    }

    auto U16 = [&](size_t o) { return (unsigned short*)(wsb + o); };
    auto F32 = [&](size_t o) { return (float*)(wsb + o); };

    // 0) zero the grid-barrier counter (ws is re-poisoned before every call)
    hipMemsetAsync(wsb + o_bar, 0, 256, stream);

    // 1) weights -> bf16 (single level; activations carry hi/lo)
    const int NW = 4 * Hd * Hd;
    cast_kernel<<<2048, 256, 0, stream>>>(Whh1, U16(o_w1), NW);
    cast_kernel<<<2048, 256, 0, stream>>>(Wih2, U16(o_w2), NW);
    cast_kernel<<<2048, 256, 0, stream>>>(Whh2, U16(o_w3), NW);
    cast_pad_kernel<<<512, 256, 0, stream>>>(Wih1, U16(o_wsm), 4 * Hd, Cd + Md, 32);

    // 2) step 0 via the proven fp32 kernel (writes h parity 0)
    {
        dim3 grid(Hd / JT, Bb / BT);
        dim3 blk(NT);
        lstm_cell_kernel<<<grid, blk, 0, stream>>>(
            h_init, Whh0, nullptr, nullptr, cond, Cd, noise, Nd, Wih0,
            bih0, bhh0, c_init, F32(o_c1), dmask, F32(o_f1), nullptr, bfc, out, 1);
        lstm_cell_kernel<<<grid, blk, 0, stream>>>(
            F32(o_f1), Wih2, h_init, Whh2, nullptr, 0, nullptr, 0, nullptr,
            bih2, bhh2, c_init, F32(o_c2), nullptr, F32(o_f2), Wfc, bfc, out, 0);
        split_kernel<<<256, 256, 0, stream>>>(F32(o_f1), U16(o_h1h), U16(o_h1l), Bb * Hd);
        split_kernel<<<256, 256, 0, stream>>>(F32(o_f2), U16(o_h2h), U16(o_h2l), Bb * Hd);
    }

    // 3) steps 1..255 in ONE persistent kernel (256 WGs = 1/CU, co-resident)
    lstm_persistent<<<256, 512, 0, stream>>>(
        U16(o_w1), U16(o_w2), U16(o_w3), U16(o_wsm),
        cond, dmask, bih1, bhh1, bih2, bhh2,
        F32(o_c1), F32(o_c2),
        U16(o_h1h), U16(o_h1l), U16(o_h2h), U16(o_h2l),
        Wfc, bfc, out, (unsigned*)(wsb + o_bar));
}

// Round 5
// 9897.400 us; speedup vs baseline: 1.1630x; 1.1630x over previous
//
#include <hip/hip_runtime.h>
#include <math.h>

// ---------------- problem constants ----------------
#define Bb   128
#define Hd   1024
#define Ld   256
#define Cd   20
#define Nd   30
#define Md   3
#define PPAR 64     // h-history depth (unique-address coherence window)

using bfrag = __attribute__((ext_vector_type(8)))  short;  // 8 bf16 (4 VGPRs)
using f16v  = __attribute__((ext_vector_type(16))) float;  // 32x32 C/D

union Pack8 { bfrag v; unsigned short u[8]; };

__device__ __forceinline__ float sigm(float x) { return 1.0f / (1.0f + expf(-x)); }

__device__ __forceinline__ unsigned short bf_rne(float x) {
    unsigned u = __float_as_uint(x);
    unsigned r = (u + 0x7fffu + ((u >> 16) & 1u)) >> 16;
    return (unsigned short)r;
}
__device__ __forceinline__ float bf_f(unsigned short h) {
    return __uint_as_float(((unsigned)h) << 16);
}

#define MFMA(a,b,c) __builtin_amdgcn_mfma_f32_32x32x16_bf16((a),(b),(c),0,0,0)

// async global->LDS, 16B/lane, PLAIN (L2-allocating: reuse within XCD).
__device__ __forceinline__ void gld_lds16(const void* g, void* s) {
    __builtin_amdgcn_global_load_lds((const __attribute__((address_space(1))) void*)g,
                                     (__attribute__((address_space(3))) void*)s, 16, 0, 0);
}
// s_waitcnt imm: vmcnt[3:0] | exp<<4 (7=off) | lgkm<<8 (15=off) | vmcnt-hi<<14
#define WAIT_VM(n)  __builtin_amdgcn_s_waitcnt(0x0F70 | (n))
#define WAIT_LGKM() __builtin_amdgcn_s_waitcnt(0xC07F)
#define SCHED_PIN() __builtin_amdgcn_sched_barrier(0)

// ---------------- preamble kernels ----------------
__global__ void cast_kernel(const float* __restrict__ src,
                            unsigned short* __restrict__ dst, int n)
{
    for (int i = blockIdx.x * blockDim.x + threadIdx.x; i < n; i += gridDim.x * blockDim.x)
        dst[i] = bf_rne(src[i]);
}

__global__ void cast_pad_kernel(const float* __restrict__ src,
                                unsigned short* __restrict__ dst,
                                int rows, int K, int Kp)
{
    int n = rows * Kp;
    for (int i = blockIdx.x * blockDim.x + threadIdx.x; i < n; i += gridDim.x * blockDim.x) {
        int r = i / Kp, k = i - r * Kp;
        dst[i] = bf_rne((k < K) ? src[r * K + k] : 0.0f);
    }
}

__global__ void split_kernel(const float* __restrict__ src,
                             unsigned short* __restrict__ hi,
                             unsigned short* __restrict__ lo, int n)
{
    for (int i = blockIdx.x * blockDim.x + threadIdx.x; i < n; i += gridDim.x * blockDim.x) {
        float x = src[i];
        unsigned short h = bf_rne(x);
        hi[i] = h;
        lo[i] = bf_rne(x - bf_f(h));
    }
}

// ---------------- persistent fused LSTM, W-in-VGPR, batch-partitioned ----------------
// Grid 256 x 512 (8 waves), 1 WG/CU. bid -> mtile=(bid&7)>>1 (XCD-pair owns a
// batch quarter), jtile=((bid&1)<<5)+(bid>>3). Tile M=32 x N=64 (4 gates x 16 j).
// Each wave pins W1/W2/W3 frags for its 128-k slice in VGPRs (192 VGPRs) and
// stages only its own A k-slice into LDS (no intra-phase barriers). h history
// has PPAR=64 parities: cross-XCD reads always miss to L3 (agent write-through).
__global__ __launch_bounds__(512, 1) void lstm_persistent(
    const unsigned short* __restrict__ W1, const unsigned short* __restrict__ W2,
    const unsigned short* __restrict__ W3, const unsigned short* __restrict__ Wsm,
    const float* __restrict__ cond, const float* __restrict__ dmask,
    const float* __restrict__ bih1, const float* __restrict__ bhh1,
    const float* __restrict__ bih2, const float* __restrict__ bhh2,
    float* __restrict__ c1, float* __restrict__ c2,
    unsigned short* __restrict__ h1h, unsigned short* __restrict__ h1l,
    unsigned short* __restrict__ h2h, unsigned short* __restrict__ h2l,
    const float* __restrict__ Wfc, const float* __restrict__ bfc,
    float* __restrict__ out, unsigned* __restrict__ barpage)
{
    __shared__ union {
        unsigned short A[2][32768];                        // 128 KB: [hi/lo][slot*8+e]
        struct { float part[8][32][65]; float hbuf[32][16]; } r;
    } U;

    const int bid   = blockIdx.x;
    const int mtile = (bid & 7) >> 1;                      // XCD-pair id
    const int jtile = ((bid & 1) << 5) + (bid >> 3);
    const int j0 = jtile * 16, m0 = mtile * 32;

    const int tid  = threadIdx.x;
    const int wave = tid >> 6;
    const int lane = tid & 63;
    const int ml   = lane & 31;
    const int q    = lane >> 5;
    const size_t S = (size_t)Bb * Hd;

    unsigned* barcnt = barpage + mtile * 64;               // 256B-separated counters
    unsigned bar_target = 0;

    const int g0 = ml >> 4, jj0 = ml & 15;
    const size_t row0 = (size_t)(g0 * Hd + j0 + jj0);      // C0 cols: gates 0/1
    const size_t row1 = (size_t)((g0 + 2) * Hd + j0 + jj0);// C1 cols: gates 2/3

    // ---- pin W frags in VGPRs: per wave, k-slice [wave*128, wave*128+128) ----
    bfrag w1f[8][2], w2f[8][2], w3f[8][2];
    #pragma unroll
    for (int i = 0; i < 8; ++i) {
        const int k = wave * 128 + 16 * i + 8 * q;
        w1f[i][0] = *(const bfrag*)(W1 + row0 * Hd + k);
        w1f[i][1] = *(const bfrag*)(W1 + row1 * Hd + k);
        w2f[i][0] = *(const bfrag*)(W2 + row0 * Hd + k);
        w2f[i][1] = *(const bfrag*)(W2 + row1 * Hd + k);
        w3f[i][0] = *(const bfrag*)(W3 + row0 * Hd + k);
        w3f[i][1] = *(const bfrag*)(W3 + row1 * Hd + k);
    }

    auto pair_bar = [&]() {
        bar_target += 64;
        __syncthreads();   // drains vmcnt -> scoped stores done before arrival
        if (tid == 0) {
            __hip_atomic_fetch_add(barcnt, 1u, __ATOMIC_RELAXED, __HIP_MEMORY_SCOPE_AGENT);
            while (__hip_atomic_load(barcnt, __ATOMIC_RELAXED, __HIP_MEMORY_SCOPE_AGENT) < bar_target)
                __builtin_amdgcn_s_sleep(2);
        }
        __syncthreads();
    };

    // stage issue i (1KB hi + 1KB lo) of this wave's own k-slice; LDS layout
    // slot = k8block*32 + m, 16B/slot -> ds_read_b128 is 512B-contiguous (no conflicts)
    auto stage_issue = [&](const unsigned short* Ah, const unsigned short* Al, int i) {
        const size_t glb = (size_t)(m0 + ml) * Hd + (16 * wave + 2 * i + q) * 8;
        const int base = (512 * wave + 64 * i) * 8;        // halfword idx, wave-uniform
        gld_lds16(Ah + glb, &U.A[0][base]);
        gld_lds16(Al + glb, &U.A[1][base]);
    };

#define KSTEP(i, wc, WF) { \
        WAIT_VM(wc); SCHED_PIN(); \
        const int hw = ((16 * wave + 2 * (i) + q) * 32 + ml) * 8; \
        bfrag ah = *(const bfrag*)&U.A[0][hw]; \
        bfrag al = *(const bfrag*)&U.A[1][hw]; \
        C0 = MFMA(ah, WF[i][0], C0); \
        C1 = MFMA(ah, WF[i][1], C1); \
        C0 = MFMA(al, WF[i][0], C0); \
        C1 = MFMA(al, WF[i][1], C1); \
    }
#define RUN8(WF) \
    KSTEP(0,14,WF) KSTEP(1,12,WF) KSTEP(2,10,WF) KSTEP(3,8,WF) \
    KSTEP(4, 6,WF) KSTEP(5, 4,WF) KSTEP(6, 2,WF) KSTEP(7,0,WF)

    auto dump_part = [&](const f16v& C0, const f16v& C1) {
        #pragma unroll
        for (int r = 0; r < 16; ++r) {
            const int mrow = (r & 3) + 8 * (r >> 2) + 4 * q;
            U.r.part[wave][mrow][ml]      = C0[r];
            U.r.part[wave][mrow][32 + ml] = C1[r];
        }
    };

    #pragma clang loop unroll(disable)
    for (int t = 1; t < Ld; ++t) {
        const int cur = t & (PPAR - 1), prv = (t - 1) & (PPAR - 1);
        float* outp_t = out + (size_t)t * Bb * Md;
        const float* outp_p = out + (size_t)(t - 1) * Bb * Md;

        // ================= phase A : cell1 =================
        {
            const unsigned short* Ah = h1h + (size_t)prv * S;
            const unsigned short* Al = h1l + (size_t)prv * S;
            SCHED_PIN();
            #pragma unroll
            for (int i = 0; i < 8; ++i) stage_issue(Ah, Al, i);
            f16v C0, C1;
            #pragma unroll
            for (int r = 0; r < 16; ++r) { C0[r] = 0.f; C1[r] = 0.f; }
            RUN8(w1f);
            SCHED_PIN();
            // out[t] init (one WG per pair; precedes FC atomics via pair_bar)
            if (jtile == 0 && tid < 32 * Md) {
                const int r = tid / Md, m = tid % Md;
                __hip_atomic_store(&outp_t[(m0 + r) * Md + m], bfc[m],
                                   __ATOMIC_RELAXED, __HIP_MEMORY_SCOPE_AGENT);
            }
            // small segment (wave 0): cat(cond[t][20], out[t-1][3]) padded to K=32
            if (wave == 0) {
                const float* crow = cond + (size_t)t * Bb * Cd + (m0 + ml) * Cd;
                const float* orow = outp_p + (m0 + ml) * Md;
                float xv[2][8];
                #pragma unroll
                for (int j = 0; j < 8; ++j) { xv[0][j] = 0.f; xv[1][j] = 0.f; }
                if (q == 0) {
                    #pragma unroll
                    for (int j = 0; j < 8; ++j) xv[0][j] = crow[j];
                    xv[1][0] = crow[16]; xv[1][1] = crow[17];
                    xv[1][2] = crow[18]; xv[1][3] = crow[19];
                    xv[1][4] = __hip_atomic_load((float*)&orow[0], __ATOMIC_RELAXED, __HIP_MEMORY_SCOPE_AGENT);
                    xv[1][5] = __hip_atomic_load((float*)&orow[1], __ATOMIC_RELAXED, __HIP_MEMORY_SCOPE_AGENT);
                    xv[1][6] = __hip_atomic_load((float*)&orow[2], __ATOMIC_RELAXED, __HIP_MEMORY_SCOPE_AGENT);
                } else {
                    #pragma unroll
                    for (int j = 0; j < 8; ++j) xv[0][j] = crow[8 + j];
                }
                #pragma unroll
                for (int ch = 0; ch < 2; ++ch) {
                    Pack8 ah, al;
                    #pragma unroll
                    for (int j = 0; j < 8; ++j) {
                        unsigned short h = bf_rne(xv[ch][j]);
                        ah.u[j] = h;
                        al.u[j] = bf_rne(xv[ch][j] - bf_f(h));
                    }
                    const int kk = ch * 16 + 8 * q;
                    bfrag b0 = *(const bfrag*)(Wsm + row0 * 32 + kk);
                    bfrag b1 = *(const bfrag*)(Wsm + row1 * 32 + kk);
                    C0 = MFMA(ah.v, b0, C0);
                    C1 = MFMA(ah.v, b1, C1);
                    C0 = MFMA(al.v, b0, C0);
                    C1 = MFMA(al.v, b1, C1);
                }
            }
            __syncthreads();
            dump_part(C0, C1);
            __syncthreads();
            if (tid < 256) {
                const int m = tid >> 3, j2 = (tid & 7) * 2;
                const int b = m0 + m, jc = j0 + j2;
                const size_t idx = (size_t)b * Hd + jc;
                float g[4][2];
                #pragma unroll
                for (int gg = 0; gg < 4; ++gg) {
                    #pragma unroll
                    for (int e = 0; e < 2; ++e) {
                        float s = 0.f;
                        #pragma unroll
                        for (int w = 0; w < 8; ++w) s += U.r.part[w][m][gg * 16 + j2 + e];
                        const int n = gg * Hd + jc + e;
                        g[gg][e] = s + bih1[n] + bhh1[n];
                    }
                }
                float2 cp = *(const float2*)&c1[idx];
                float2 mv = *(const float2*)&dmask[(size_t)t * S + idx];
                float cn0 = sigm(g[1][0]) * cp.x + sigm(g[0][0]) * tanhf(g[2][0]);
                float cn1 = sigm(g[1][1]) * cp.y + sigm(g[0][1]) * tanhf(g[2][1]);
                float hv0 = sigm(g[3][0]) * tanhf(cn0) * mv.x;
                float hv1 = sigm(g[3][1]) * tanhf(cn1) * mv.y;
                *(float2*)&c1[idx] = make_float2(cn0, cn1);
                unsigned short h0 = bf_rne(hv0), h1_ = bf_rne(hv1);
                unsigned hp = (unsigned)h0 | ((unsigned)h1_ << 16);
                unsigned lp = (unsigned)bf_rne(hv0 - bf_f(h0)) | ((unsigned)bf_rne(hv1 - bf_f(h1_)) << 16);
                __hip_atomic_store((unsigned*)&h1h[(size_t)cur * S + idx], hp, __ATOMIC_RELAXED, __HIP_MEMORY_SCOPE_AGENT);
                __hip_atomic_store((unsigned*)&h1l[(size_t)cur * S + idx], lp, __ATOMIC_RELAXED, __HIP_MEMORY_SCOPE_AGENT);
            }
            pair_bar();
        }

        // ================= phase B : cell2 =================
        {
            const unsigned short* A2h = h1h + (size_t)cur * S;
            const unsigned short* A2l = h1l + (size_t)cur * S;
            const unsigned short* A3h = h2h + (size_t)prv * S;
            const unsigned short* A3l = h2l + (size_t)prv * S;
            f16v C0, C1;
            #pragma unroll
            for (int r = 0; r < 16; ++r) { C0[r] = 0.f; C1[r] = 0.f; }
            SCHED_PIN();
            #pragma unroll
            for (int i = 0; i < 8; ++i) stage_issue(A2h, A2l, i);
            RUN8(w2f);
            WAIT_LGKM(); SCHED_PIN();        // last ds_reads done before overwrite
            #pragma unroll
            for (int i = 0; i < 8; ++i) stage_issue(A3h, A3l, i);
            RUN8(w3f);
            SCHED_PIN();
            __syncthreads();
            dump_part(C0, C1);
            __syncthreads();
            if (tid < 256) {
                const int m = tid >> 3, j2 = (tid & 7) * 2;
                const int b = m0 + m, jc = j0 + j2;
                const size_t idx = (size_t)b * Hd + jc;
                float g[4][2];
                #pragma unroll
                for (int gg = 0; gg < 4; ++gg) {
                    #pragma unroll
                    for (int e = 0; e < 2; ++e) {
                        float s = 0.f;
                        #pragma unroll
                        for (int w = 0; w < 8; ++w) s += U.r.part[w][m][gg * 16 + j2 + e];
                        const int n = gg * Hd + jc + e;
                        g[gg][e] = s + bih2[n] + bhh2[n];
                    }
                }
                float2 cp = *(const float2*)&c2[idx];
                float cn0 = sigm(g[1][0]) * cp.x + sigm(g[0][0]) * tanhf(g[2][0]);
                float cn1 = sigm(g[1][1]) * cp.y + sigm(g[0][1]) * tanhf(g[2][1]);
                float hv0 = sigm(g[3][0]) * tanhf(cn0);
                float hv1 = sigm(g[3][1]) * tanhf(cn1);
                *(float2*)&c2[idx] = make_float2(cn0, cn1);
                U.r.hbuf[m][j2]     = hv0;
                U.r.hbuf[m][j2 + 1] = hv1;
                unsigned short h0 = bf_rne(hv0), h1_ = bf_rne(hv1);
                unsigned hp = (unsigned)h0 | ((unsigned)h1_ << 16);
                unsigned lp = (unsigned)bf_rne(hv0 - bf_f(h0)) | ((unsigned)bf_rne(hv1 - bf_f(h1_)) << 16);
                __hip_atomic_store((unsigned*)&h2h[(size_t)cur * S + idx], hp, __ATOMIC_RELAXED, __HIP_MEMORY_SCOPE_AGENT);
                __hip_atomic_store((unsigned*)&h2l[(size_t)cur * S + idx], lp, __ATOMIC_RELAXED, __HIP_MEMORY_SCOPE_AGENT);
            }
            __syncthreads();
            if (tid < 32) {
                const int b = m0 + tid;
                #pragma unroll
                for (int mm = 0; mm < Md; ++mm) {
                    float s = 0.0f;
                    #pragma unroll
                    for (int jj = 0; jj < 16; ++jj) s += U.r.hbuf[tid][jj] * Wfc[mm * Hd + j0 + jj];
                    atomicAdd(&outp_t[b * Md + mm], s);
                }
            }
            pair_bar();
        }
    }
#undef KSTEP
#undef RUN8
}

// ---------------- R0 fp32 VALU cell kernel (step 0 + ws fallback) ----------------
#define BT   64
#define JT   8
#define RT   32
#define KC   64
#define NT   256
#define NCHUNK 16
#define XSs  68
#define SMs  52
#define GBs  33

__global__ __launch_bounds__(NT) void lstm_cell_kernel(
    const float* __restrict__ Xbig0, const float* __restrict__ Wbig0,
    const float* __restrict__ Xbig1, const float* __restrict__ Wbig1,
    const float* __restrict__ Xsm0p, int K0,
    const float* __restrict__ Xsm1p, int K1,
    const float* __restrict__ Wsmall,
    const float* __restrict__ bih, const float* __restrict__ bhh,
    const float* __restrict__ cprev, float* __restrict__ cnew,
    const float* __restrict__ mask,
    float* __restrict__ hnew,
    const float* __restrict__ Wfc, const float* __restrict__ bfc,
    float* __restrict__ outp, int initOut)
{
    __shared__ float Xs[BT][XSs];
    __shared__ float Ws[RT][XSs];
    __shared__ float gbuf[BT][GBs];
    __shared__ float hbuf[BT][JT];
    __shared__ float Xsm[BT][SMs];
    __shared__ float Wsm[RT][SMs];

    const int tid = threadIdx.x;
    const int j0  = blockIdx.x * JT;
    const int b0  = blockIdx.y * BT;
    const int jp  = tid & 15;
    const int bq  = tid >> 4;

    auto GROW = [&](int r) { return ((r >> 3) * Hd + j0 + (r & 7)); };

    float acc[4][2];
    #pragma unroll
    for (int i = 0; i < 4; ++i) { acc[i][0] = 0.f; acc[i][1] = 0.f; }

    if (initOut && blockIdx.x == 0 && blockIdx.y == 0) {
        for (int i = tid; i < Bb * 3; i += NT) outp[i] = bfc[i % 3];
    }

    for (int seg = 0; seg < 2; ++seg) {
        const float* __restrict__ Xg = (seg == 0) ? Xbig0 : Xbig1;
        const float* __restrict__ Wg = (seg == 0) ? Wbig0 : Wbig1;
        if (Xg == nullptr) continue;

        float4 xr[4], wr[2];
        #pragma unroll
        for (int p = 0; p < 4; ++p) {
            int fi = p * NT + tid; int bloc = fi >> 4; int kq = fi & 15;
            xr[p] = *(const float4*)(Xg + (size_t)(b0 + bloc) * Hd + kq * 4);
        }
        #pragma unroll
        for (int p = 0; p < 2; ++p) {
            int fi = p * NT + tid; int r = fi >> 4; int kq = fi & 15;
            wr[p] = *(const float4*)(Wg + (size_t)GROW(r) * Hd + kq * 4);
        }
        #pragma unroll
        for (int p = 0; p < 4; ++p) { int fi = p * NT + tid; *(float4*)&Xs[fi >> 4][(fi & 15) * 4] = xr[p]; }
        #pragma unroll
        for (int p = 0; p < 2; ++p) { int fi = p * NT + tid; *(float4*)&Ws[fi >> 4][(fi & 15) * 4] = wr[p]; }
        __syncthreads();

        for (int kc = 0; kc < NCHUNK; ++kc) {
            const bool more = (kc + 1) < NCHUNK;
            if (more) {
                const int k0n = (kc + 1) * KC;
                #pragma unroll
                for (int p = 0; p < 4; ++p) {
                    int fi = p * NT + tid; int bloc = fi >> 4; int kq = fi & 15;
                    xr[p] = *(const float4*)(Xg + (size_t)(b0 + bloc) * Hd + k0n + kq * 4);
                }
                #pragma unroll
                for (int p = 0; p < 2; ++p) {
                    int fi = p * NT + tid; int r = fi >> 4; int kq = fi & 15;
                    wr[p] = *(const float4*)(Wg + (size_t)GROW(r) * Hd + k0n + kq * 4);
                }
            }
            #pragma unroll 4
            for (int kk = 0; kk < KC; kk += 4) {
                float4 w0 = *(const float4*)&Ws[jp][kk];
                float4 w1 = *(const float4*)&Ws[jp + 16][kk];
                #pragma unroll
                for (int bb = 0; bb < 4; ++bb) {
                    float4 xvv = *(const float4*)&Xs[bq + 16 * bb][kk];
                    acc[bb][0] += xvv.x * w0.x + xvv.y * w0.y + xvv.z * w0.z + xvv.w * w0.w;
                    acc[bb][1] += xvv.x * w1.x + xvv.y * w1.y + xvv.z * w1.z + xvv.w * w1.w;
                }
            }
            __syncthreads();
            if (more) {
                #pragma unroll
                for (int p = 0; p < 4; ++p) { int fi = p * NT + tid; *(float4*)&Xs[fi >> 4][(fi & 15) * 4] = xr[p]; }
                #pragma unroll
                for (int p = 0; p < 2; ++p) { int fi = p * NT + tid; *(float4*)&Ws[fi >> 4][(fi & 15) * 4] = wr[p]; }
                __syncthreads();
            }
        }
    }

    if (Wsmall) {
        const int Kt = K0 + K1;
        for (int i = tid; i < BT * Kt; i += NT) {
            int bloc = i / Kt, k = i % Kt;
            Xsm[bloc][k] = (k < K0) ? Xsm0p[(size_t)(b0 + bloc) * K0 + k]
                                    : Xsm1p[(size_t)(b0 + bloc) * K1 + (k - K0)];
        }
        for (int i = tid; i < RT * Kt; i += NT) {
            int r = i / Kt, k = i % Kt;
            Wsm[r][k] = Wsmall[(size_t)GROW(r) * Kt + k];
        }
        __syncthreads();
        for (int k = 0; k < Kt; ++k) {
            float w0 = Wsm[jp][k], w1 = Wsm[jp + 16][k];
            #pragma unroll
            for (int bb = 0; bb < 4; ++bb) {
                float xvv = Xsm[bq + 16 * bb][k];
                acc[bb][0] += xvv * w0;
                acc[bb][1] += xvv * w1;
            }
        }
    }

    __syncthreads();
    #pragma unroll
    for (int bb = 0; bb < 4; ++bb) {
        gbuf[bq + 16 * bb][jp]      = acc[bb][0];
        gbuf[bq + 16 * bb][jp + 16] = acc[bb][1];
    }
    __syncthreads();

    for (int p = tid; p < BT * JT; p += NT) {
        int bloc = p & (BT - 1);
        int j    = p >> 6;
        int bg   = b0 + bloc;
        int jc   = j0 + j;
        float gi = gbuf[bloc][j]      + bih[jc]          + bhh[jc];
        float gf = gbuf[bloc][8 + j]  + bih[Hd + jc]     + bhh[Hd + jc];
        float gg = gbuf[bloc][16 + j] + bih[2 * Hd + jc] + bhh[2 * Hd + jc];
        float go = gbuf[bloc][24 + j] + bih[3 * Hd + jc] + bhh[3 * Hd + jc];
        float cp = cprev[(size_t)bg * Hd + jc];
        float cn = sigm(gf) * cp + sigm(gi) * tanhf(gg);
        float hv = sigm(go) * tanhf(cn);
        if (mask) hv *= mask[(size_t)bg * Hd + jc];
        cnew[(size_t)bg * Hd + jc] = cn;
        hnew[(size_t)bg * Hd + jc] = hv;
        hbuf[bloc][j] = hv;
    }

    if (Wfc) {
        __syncthreads();
        if (tid < BT) {
            int bg = b0 + tid;
            #pragma unroll
            for (int m = 0; m < 3; ++m) {
                float s = 0.f;
                #pragma unroll
                for (int j = 0; j < JT; ++j) s += hbuf[tid][j] * Wfc[m * Hd + j0 + j];
                atomicAdd(&outp[bg * 3 + m], s);
            }
        }
    }
}

// ---------------- launch ----------------
extern "C" void kernel_launch(void* const* d_in, const int* in_sizes, int n_in,
                              void* d_out, int out_size, void* d_ws, size_t ws_size,
                              hipStream_t stream)
{
    (void)in_sizes; (void)n_in; (void)out_size;
    const float* cond   = (const float*)d_in[0];
    const float* noise  = (const float*)d_in[1];
    const float* h_init = (const float*)d_in[2];
    const float* c_init = (const float*)d_in[3];
    const float* dmask  = (const float*)d_in[4];
    const float* Wih0   = (const float*)d_in[5];
    const float* Whh0   = (const float*)d_in[6];
    const float* bih0   = (const float*)d_in[7];
    const float* bhh0   = (const float*)d_in[8];
    const float* Wih1   = (const float*)d_in[9];
    const float* Whh1   = (const float*)d_in[10];
    const float* bih1   = (const float*)d_in[11];
    const float* bhh1   = (const float*)d_in[12];
    const float* Wih2   = (const float*)d_in[13];
    const float* Whh2   = (const float*)d_in[14];
    const float* bih2   = (const float*)d_in[15];
    const float* bhh2   = (const float*)d_in[16];
    const float* Wfc    = (const float*)d_in[17];
    const float* bfc    = (const float*)d_in[18];
    float* out = (float*)d_out;

    char* wsb = (char*)d_ws;
    size_t off = 0;
    auto alloc = [&](size_t bytes) { size_t o = off; off += (bytes + 255) & ~(size_t)255; return o; };

    const size_t WBIG = (size_t)4 * Hd * Hd * 2;     // 4096x1024 bf16
    const size_t S    = (size_t)Bb * Hd;
    const size_t HBP  = S * 2 * PPAR;                // bf16 h history, PPAR parities
    const size_t HF   = S * 4;                       // fp32

    size_t o_w1 = alloc(WBIG);                        // Whh1 bf16
    size_t o_w2 = alloc(WBIG);                        // Wih2 bf16
    size_t o_w3 = alloc(WBIG);                        // Whh2 bf16
    size_t o_wsm = alloc((size_t)4 * Hd * 32 * 2);    // Wih1 padded bf16
    size_t o_h1h = alloc(HBP), o_h1l = alloc(HBP);
    size_t o_h2h = alloc(HBP), o_h2l = alloc(HBP);
    size_t o_c1 = alloc(HF), o_c2 = alloc(HF);
    size_t o_f1 = alloc(HF), o_f2 = alloc(HF);
    off = (off + 4095) & ~(size_t)4095;
    size_t o_bar = alloc(4096);
    const size_t needed = off;

    if (ws_size < needed) {
        // -------- fallback: full R0 fp32 path --------
        float* ws = (float*)d_ws;
        float* h1a = ws;         float* h1b = ws + S;
        float* h2a = ws + 2 * S; float* h2b = ws + 3 * S;
        float* c1  = ws + 4 * S; float* c2  = ws + 5 * S;
        dim3 grid(Hd / JT, Bb / BT);
        dim3 blk(NT);
        lstm_cell_kernel<<<grid, blk, 0, stream>>>(
            h_init, Whh0, nullptr, nullptr, cond, Cd, noise, Nd, Wih0,
            bih0, bhh0, c_init, c1, dmask, h1a, nullptr, bfc, out, 1);
        lstm_cell_kernel<<<grid, blk, 0, stream>>>(
            h1a, Wih2, h_init, Whh2, nullptr, 0, nullptr, 0, nullptr,
            bih2, bhh2, c_init, c2, nullptr, h2a, Wfc, bfc, out, 0);
        const float* h1prev = h1a; const float* h2prev = h2a;
        for (int t = 1; t < Ld; ++t) {
            float* h1cur = (t & 1) ? h1b : h1a;
            float* h2cur = (t & 1) ? h2b : h2a;
            lstm_cell_kernel<<<grid, blk, 0, stream>>>(
                h1prev, Whh1, nullptr, nullptr,
                cond + (size_t)t * Bb * Cd, Cd, out + (size_t)(t - 1) * Bb * Md, Md, Wih1,
                bih1, bhh1, c1, c1, dmask + (size_t)t * Bb * Hd, h1cur,
                nullptr, bfc, out + (size_t)t * Bb * Md, 1);
            lstm_cell_kernel<<<grid, blk, 0, stream>>>(
                h1cur, Wih2, h2prev, Whh2, nullptr, 0, nullptr, 0, nullptr,
                bih2, bhh2, c2, c2, nullptr, h2cur, Wfc, bfc, out + (size_t)t * Bb * Md, 0);
            h1prev = h1cur; h2prev = h2cur;
        }
        return;
    }

    auto U16 = [&](size_t o) { return (unsigned short*)(wsb + o); };
    auto F32 = [&](size_t o) { return (float*)(wsb + o); };

    // 0) zero the pair-barrier counters
    hipMemsetAsync(wsb + o_bar, 0, 1024, stream);

    // 1) weights -> bf16 (single level; activations carry hi/lo)
    const int NW = 4 * Hd * Hd;
    cast_kernel<<<2048, 256, 0, stream>>>(Whh1, U16(o_w1), NW);
    cast_kernel<<<2048, 256, 0, stream>>>(Wih2, U16(o_w2), NW);
    cast_kernel<<<2048, 256, 0, stream>>>(Whh2, U16(o_w3), NW);
    cast_pad_kernel<<<512, 256, 0, stream>>>(Wih1, U16(o_wsm), 4 * Hd, Cd + Md, 32);

    // 2) step 0 via the proven fp32 kernel (writes h parity 0)
    {
        dim3 grid(Hd / JT, Bb / BT);
        dim3 blk(NT);
        lstm_cell_kernel<<<grid, blk, 0, stream>>>(
            h_init, Whh0, nullptr, nullptr, cond, Cd, noise, Nd, Wih0,
            bih0, bhh0, c_init, F32(o_c1), dmask, F32(o_f1), nullptr, bfc, out, 1);
        lstm_cell_kernel<<<grid, blk, 0, stream>>>(
            F32(o_f1), Wih2, h_init, Whh2, nullptr, 0, nullptr, 0, nullptr,
            bih2, bhh2, c_init, F32(o_c2), nullptr, F32(o_f2), Wfc, bfc, out, 0);
        split_kernel<<<256, 256, 0, stream>>>(F32(o_f1), U16(o_h1h), U16(o_h1l), Bb * Hd);
        split_kernel<<<256, 256, 0, stream>>>(F32(o_f2), U16(o_h2h), U16(o_h2l), Bb * Hd);
    }

    // 3) steps 1..255 in ONE persistent kernel (256 WGs, 4 independent pair-groups)
    lstm_persistent<<<256, 512, 0, stream>>>(
        U16(o_w1), U16(o_w2), U16(o_w3), U16(o_wsm),
        cond, dmask, bih1, bhh1, bih2, bhh2,
        F32(o_c1), F32(o_c2),
        U16(o_h1h), U16(o_h1l), U16(o_h2h), U16(o_h2l),
        Wfc, bfc, out, (unsigned*)(wsb + o_bar));
}

// Round 6
// 8036.037 us; speedup vs baseline: 1.4324x; 1.2316x over previous
//
#include <hip/hip_runtime.h>
#include <math.h>

// ---------------- problem constants ----------------
#define Bb   128
#define Hd   1024
#define Ld   256
#define Cd   20
#define Nd   30
#define Md   3
#define PPAR 64     // h-history depth (unique-address coherence window)

using bfrag = __attribute__((ext_vector_type(8)))  short;  // 8 bf16 (4 VGPRs)
using f16v  = __attribute__((ext_vector_type(16))) float;  // 32x32 C/D

union Pack8 { bfrag v; unsigned short u[8]; };

__device__ __forceinline__ float sigm(float x) { return 1.0f / (1.0f + expf(-x)); }

__device__ __forceinline__ unsigned short bf_rne(float x) {
    unsigned u = __float_as_uint(x);
    unsigned r = (u + 0x7fffu + ((u >> 16) & 1u)) >> 16;
    return (unsigned short)r;
}
__device__ __forceinline__ float bf_f(unsigned short h) {
    return __uint_as_float(((unsigned)h) << 16);
}

#define MFMA(a,b,c) __builtin_amdgcn_mfma_f32_32x32x16_bf16((a),(b),(c),0,0,0)

// async global->LDS, 16B/lane, PLAIN (L2-allocating).
__device__ __forceinline__ void gld_lds16(const void* g, void* s) {
    __builtin_amdgcn_global_load_lds((const __attribute__((address_space(1))) void*)g,
                                     (__attribute__((address_space(3))) void*)s, 16, 0, 0);
}
// s_waitcnt imm: vmcnt[3:0] | exp<<4 (7=off) | lgkm<<8 (15=off)
#define WAIT_VM(n)  __builtin_amdgcn_s_waitcnt(0x0F70 | (n))
#define WAIT_LGKM() __builtin_amdgcn_s_waitcnt(0xC07F)

// ---------------- preamble kernels ----------------
__global__ void cast_kernel(const float* __restrict__ src,
                            unsigned short* __restrict__ dst, int n)
{
    for (int i = blockIdx.x * blockDim.x + threadIdx.x; i < n; i += gridDim.x * blockDim.x)
        dst[i] = bf_rne(src[i]);
}

__global__ void cast_pad_kernel(const float* __restrict__ src,
                                unsigned short* __restrict__ dst,
                                int rows, int K, int Kp)
{
    int n = rows * Kp;
    for (int i = blockIdx.x * blockDim.x + threadIdx.x; i < n; i += gridDim.x * blockDim.x) {
        int r = i / Kp, k = i - r * Kp;
        dst[i] = bf_rne((k < K) ? src[r * K + k] : 0.0f);
    }
}

// fp32 flat [b][j] -> bf16 hi/lo in k-blocked layout [j>>3][b][j&7]
__global__ void split_blocked_kernel(const float* __restrict__ src,
                                     unsigned short* __restrict__ hi,
                                     unsigned short* __restrict__ lo)
{
    int i = blockIdx.x * blockDim.x + threadIdx.x;
    if (i < Bb * Hd) {
        int b = i / Hd, j = i % Hd;
        float x = src[i];
        unsigned short h = bf_rne(x);
        size_t d = (size_t)((j >> 3) * Bb + b) * 8 + (j & 7);
        hi[d] = h;
        lo[d] = bf_rne(x - bf_f(h));
    }
}

// ---------------- persistent fused LSTM, W-in-VGPR (forced), batch-partitioned ----------------
// Grid 256 x 512 (8 waves), 1 WG/CU. mtile=(bid&7)>>1 (XCD-pair owns batch
// quarter), jtile=((bid&1)<<5)+(bid>>3). Tile M=32 x N=64 (4 gates x 16 j).
// Each wave pins W1/W2/W3 frags for its 128-k slice in VGPRs (asm-pinned, 192
// VGPRs) and stages its A k-slice into LDS via coalesced global_load_lds from
// the k-blocked h layout. h history: PPAR=64 parities, agent-scope stores.
__global__ __launch_bounds__(512, 1) void lstm_persistent(
    const unsigned short* __restrict__ W1, const unsigned short* __restrict__ W2,
    const unsigned short* __restrict__ W3, const unsigned short* __restrict__ Wsm,
    const float* __restrict__ cond, const float* __restrict__ dmask,
    const float* __restrict__ bih1, const float* __restrict__ bhh1,
    const float* __restrict__ bih2, const float* __restrict__ bhh2,
    float* __restrict__ c1, float* __restrict__ c2,
    unsigned short* __restrict__ h1h, unsigned short* __restrict__ h1l,
    unsigned short* __restrict__ h2h, unsigned short* __restrict__ h2l,
    const float* __restrict__ Wfc, const float* __restrict__ bfc,
    float* __restrict__ out, unsigned* __restrict__ barpage)
{
    __shared__ union {
        unsigned short A[2][32768];                        // [hi/lo][wave*4096 + rb*256 + ml*8]
        struct { float part[8][32][65]; float hbuf[32][16]; } r;
    } U;

    const int bid   = blockIdx.x;
    const int mtile = (bid & 7) >> 1;                      // XCD-pair id
    const int jtile = ((bid & 1) << 5) + (bid >> 3);
    const int j0 = jtile * 16, m0 = mtile * 32;

    const int tid  = threadIdx.x;
    const int wave = tid >> 6;
    const int lane = tid & 63;
    const int ml   = lane & 31;
    const int q    = lane >> 5;
    const size_t S = (size_t)Bb * Hd;

    unsigned* barcnt = barpage + mtile * 64;               // 256B-separated counters
    unsigned bar_target = 0;

    const int g0 = ml >> 4, jj0 = ml & 15;
    const size_t row0 = (size_t)(g0 * Hd + j0 + jj0);      // C0 cols: gates 0/1
    const size_t row1 = (size_t)((g0 + 2) * Hd + j0 + jj0);// C1 cols: gates 2/3

    // ---- pin W frags in VGPRs: per wave, k-slice [wave*128, wave*128+128) ----
    bfrag w1f[8][2], w2f[8][2], w3f[8][2];
    #pragma unroll
    for (int i = 0; i < 8; ++i) {
        const int k = wave * 128 + 16 * i + 8 * q;
        w1f[i][0] = *(const bfrag*)(W1 + row0 * Hd + k);
        w1f[i][1] = *(const bfrag*)(W1 + row1 * Hd + k);
        w2f[i][0] = *(const bfrag*)(W2 + row0 * Hd + k);
        w2f[i][1] = *(const bfrag*)(W2 + row1 * Hd + k);
        w3f[i][0] = *(const bfrag*)(W3 + row0 * Hd + k);
        w3f[i][1] = *(const bfrag*)(W3 + row1 * Hd + k);
    }
    // force residency: values become asm-defined -> no rematerialization
    #pragma unroll
    for (int i = 0; i < 8; ++i) {
        asm volatile("" : "+v"(w1f[i][0]), "+v"(w1f[i][1]),
                          "+v"(w2f[i][0]), "+v"(w2f[i][1]),
                          "+v"(w3f[i][0]), "+v"(w3f[i][1]));
    }

    auto pair_bar = [&]() {
        bar_target += 64;
        __syncthreads();   // drains vmcnt -> scoped stores done before arrival
        if (tid == 0) {
            __hip_atomic_fetch_add(barcnt, 1u, __ATOMIC_RELAXED, __HIP_MEMORY_SCOPE_AGENT);
            while (__hip_atomic_load(barcnt, __ATOMIC_RELAXED, __HIP_MEMORY_SCOPE_AGENT) < bar_target)
                __builtin_amdgcn_s_sleep(2);
        }
        __syncthreads();
    };

    // stage issue i: two k8-blocks (lanes 0-31 -> block 2i, 32-63 -> 2i+1 of this
    // wave's 16-block slice), fully coalesced (2x 512B contiguous), hi + lo.
    auto stage_issue = [&](const unsigned short* Ah, const unsigned short* Al, int i) {
        const size_t g = (size_t)((wave * 16 + 2 * i + q) * Bb + m0 + ml) * 8;
        const int base = wave * 4096 + i * 512;            // halfwords, wave-uniform
        gld_lds16(Ah + g, &U.A[0][base]);
        gld_lds16(Al + g, &U.A[1][base]);
    };

#define KSTEP(i, wc, WF) { \
        WAIT_VM(wc); \
        const int hw = wave * 4096 + (2 * (i) + q) * 256 + ml * 8; \
        bfrag ah = *(const bfrag*)&U.A[0][hw]; \
        bfrag al = *(const bfrag*)&U.A[1][hw]; \
        C0 = MFMA(ah, WF[i][0], C0); \
        C1 = MFMA(ah, WF[i][1], C1); \
        C0 = MFMA(al, WF[i][0], C0); \
        C1 = MFMA(al, WF[i][1], C1); \
    }
#define RUN8(WF) \
    KSTEP(0,14,WF) KSTEP(1,12,WF) KSTEP(2,10,WF) KSTEP(3,8,WF) \
    KSTEP(4, 6,WF) KSTEP(5, 4,WF) KSTEP(6, 2,WF) KSTEP(7,0,WF)

    auto dump_part = [&](const f16v& C0, const f16v& C1) {
        #pragma unroll
        for (int r = 0; r < 16; ++r) {
            const int mrow = (r & 3) + 8 * (r >> 2) + 4 * q;
            U.r.part[wave][mrow][ml]      = C0[r];
            U.r.part[wave][mrow][32 + ml] = C1[r];
        }
    };

    #pragma clang loop unroll(disable)
    for (int t = 1; t < Ld; ++t) {
        const int cur = t & (PPAR - 1), prv = (t - 1) & (PPAR - 1);
        float* outp_t = out + (size_t)t * Bb * Md;
        const float* outp_p = out + (size_t)(t - 1) * Bb * Md;

        // ================= phase A : cell1 =================
        {
            const unsigned short* Ah = h1h + (size_t)prv * S;
            const unsigned short* Al = h1l + (size_t)prv * S;
            #pragma unroll
            for (int i = 0; i < 8; ++i) stage_issue(Ah, Al, i);
            f16v C0, C1;
            #pragma unroll
            for (int r = 0; r < 16; ++r) { C0[r] = 0.f; C1[r] = 0.f; }
            RUN8(w1f);
            // out[t] init (one WG per pair; precedes FC atomics via pair_bar)
            if (jtile == 0 && tid < 32 * Md) {
                const int r = tid / Md, m = tid % Md;
                __hip_atomic_store(&outp_t[(m0 + r) * Md + m], bfc[m],
                                   __ATOMIC_RELAXED, __HIP_MEMORY_SCOPE_AGENT);
            }
            // small segment (wave 0): cat(cond[t][20], out[t-1][3]) padded to K=32
            if (wave == 0) {
                const float* crow = cond + (size_t)t * Bb * Cd + (m0 + ml) * Cd;
                const float* orow = outp_p + (m0 + ml) * Md;
                float xv[2][8];
                #pragma unroll
                for (int j = 0; j < 8; ++j) { xv[0][j] = 0.f; xv[1][j] = 0.f; }
                if (q == 0) {
                    #pragma unroll
                    for (int j = 0; j < 8; ++j) xv[0][j] = crow[j];
                    xv[1][0] = crow[16]; xv[1][1] = crow[17];
                    xv[1][2] = crow[18]; xv[1][3] = crow[19];
                    xv[1][4] = __hip_atomic_load((float*)&orow[0], __ATOMIC_RELAXED, __HIP_MEMORY_SCOPE_AGENT);
                    xv[1][5] = __hip_atomic_load((float*)&orow[1], __ATOMIC_RELAXED, __HIP_MEMORY_SCOPE_AGENT);
                    xv[1][6] = __hip_atomic_load((float*)&orow[2], __ATOMIC_RELAXED, __HIP_MEMORY_SCOPE_AGENT);
                } else {
                    #pragma unroll
                    for (int j = 0; j < 8; ++j) xv[0][j] = crow[8 + j];
                }
                #pragma unroll
                for (int ch = 0; ch < 2; ++ch) {
                    Pack8 ah, al;
                    #pragma unroll
                    for (int j = 0; j < 8; ++j) {
                        unsigned short h = bf_rne(xv[ch][j]);
                        ah.u[j] = h;
                        al.u[j] = bf_rne(xv[ch][j] - bf_f(h));
                    }
                    const int kk = ch * 16 + 8 * q;
                    bfrag b0 = *(const bfrag*)(Wsm + row0 * 32 + kk);
                    bfrag b1 = *(const bfrag*)(Wsm + row1 * 32 + kk);
                    C0 = MFMA(ah.v, b0, C0);
                    C1 = MFMA(ah.v, b1, C1);
                    C0 = MFMA(al.v, b0, C0);
                    C1 = MFMA(al.v, b1, C1);
                }
            }
            __syncthreads();
            dump_part(C0, C1);
            __syncthreads();
            if (tid < 256) {
                const int m = tid >> 3, j2 = (tid & 7) * 2;
                const int b = m0 + m, jc = j0 + j2;
                const size_t idx = (size_t)b * Hd + jc;
                const size_t bidx = (size_t)((jc >> 3) * Bb + b) * 8 + (jc & 7);
                float g[4][2];
                #pragma unroll
                for (int gg = 0; gg < 4; ++gg) {
                    #pragma unroll
                    for (int e = 0; e < 2; ++e) {
                        float s = 0.f;
                        #pragma unroll
                        for (int w = 0; w < 8; ++w) s += U.r.part[w][m][gg * 16 + j2 + e];
                        const int n = gg * Hd + jc + e;
                        g[gg][e] = s + bih1[n] + bhh1[n];
                    }
                }
                float2 cp = *(const float2*)&c1[idx];
                float2 mv = *(const float2*)&dmask[(size_t)t * S + idx];
                float cn0 = sigm(g[1][0]) * cp.x + sigm(g[0][0]) * tanhf(g[2][0]);
                float cn1 = sigm(g[1][1]) * cp.y + sigm(g[0][1]) * tanhf(g[2][1]);
                float hv0 = sigm(g[3][0]) * tanhf(cn0) * mv.x;
                float hv1 = sigm(g[3][1]) * tanhf(cn1) * mv.y;
                *(float2*)&c1[idx] = make_float2(cn0, cn1);
                unsigned short h0 = bf_rne(hv0), h1_ = bf_rne(hv1);
                unsigned hp = (unsigned)h0 | ((unsigned)h1_ << 16);
                unsigned lp = (unsigned)bf_rne(hv0 - bf_f(h0)) | ((unsigned)bf_rne(hv1 - bf_f(h1_)) << 16);
                __hip_atomic_store((unsigned*)&h1h[(size_t)cur * S + bidx], hp, __ATOMIC_RELAXED, __HIP_MEMORY_SCOPE_AGENT);
                __hip_atomic_store((unsigned*)&h1l[(size_t)cur * S + bidx], lp, __ATOMIC_RELAXED, __HIP_MEMORY_SCOPE_AGENT);
            }
            pair_bar();
        }

        // ================= phase B : cell2 =================
        {
            const unsigned short* A2h = h1h + (size_t)cur * S;
            const unsigned short* A2l = h1l + (size_t)cur * S;
            const unsigned short* A3h = h2h + (size_t)prv * S;
            const unsigned short* A3l = h2l + (size_t)prv * S;
            f16v C0, C1;
            #pragma unroll
            for (int r = 0; r < 16; ++r) { C0[r] = 0.f; C1[r] = 0.f; }
            #pragma unroll
            for (int i = 0; i < 8; ++i) stage_issue(A2h, A2l, i);
            RUN8(w2f);
            WAIT_LGKM();                 // last ds_reads done before overwrite
            #pragma unroll
            for (int i = 0; i < 8; ++i) stage_issue(A3h, A3l, i);
            RUN8(w3f);
            __syncthreads();
            dump_part(C0, C1);
            __syncthreads();
            if (tid < 256) {
                const int m = tid >> 3, j2 = (tid & 7) * 2;
                const int b = m0 + m, jc = j0 + j2;
                const size_t idx = (size_t)b * Hd + jc;
                const size_t bidx = (size_t)((jc >> 3) * Bb + b) * 8 + (jc & 7);
                float g[4][2];
                #pragma unroll
                for (int gg = 0; gg < 4; ++gg) {
                    #pragma unroll
                    for (int e = 0; e < 2; ++e) {
                        float s = 0.f;
                        #pragma unroll
                        for (int w = 0; w < 8; ++w) s += U.r.part[w][m][gg * 16 + j2 + e];
                        const int n = gg * Hd + jc + e;
                        g[gg][e] = s + bih2[n] + bhh2[n];
                    }
                }
                float2 cp = *(const float2*)&c2[idx];
                float cn0 = sigm(g[1][0]) * cp.x + sigm(g[0][0]) * tanhf(g[2][0]);
                float cn1 = sigm(g[1][1]) * cp.y + sigm(g[0][1]) * tanhf(g[2][1]);
                float hv0 = sigm(g[3][0]) * tanhf(cn0);
                float hv1 = sigm(g[3][1]) * tanhf(cn1);
                *(float2*)&c2[idx] = make_float2(cn0, cn1);
                U.r.hbuf[m][j2]     = hv0;
                U.r.hbuf[m][j2 + 1] = hv1;
                unsigned short h0 = bf_rne(hv0), h1_ = bf_rne(hv1);
                unsigned hp = (unsigned)h0 | ((unsigned)h1_ << 16);
                unsigned lp = (unsigned)bf_rne(hv0 - bf_f(h0)) | ((unsigned)bf_rne(hv1 - bf_f(h1_)) << 16);
                __hip_atomic_store((unsigned*)&h2h[(size_t)cur * S + bidx], hp, __ATOMIC_RELAXED, __HIP_MEMORY_SCOPE_AGENT);
                __hip_atomic_store((unsigned*)&h2l[(size_t)cur * S + bidx], lp, __ATOMIC_RELAXED, __HIP_MEMORY_SCOPE_AGENT);
            }
            __syncthreads();
            if (tid < 32) {
                const int b = m0 + tid;
                #pragma unroll
                for (int mm = 0; mm < Md; ++mm) {
                    float s = 0.0f;
                    #pragma unroll
                    for (int jj = 0; jj < 16; ++jj) s += U.r.hbuf[tid][jj] * Wfc[mm * Hd + j0 + jj];
                    atomicAdd(&outp_t[b * Md + mm], s);
                }
            }
            pair_bar();
        }
    }
#undef KSTEP
#undef RUN8
}

// ---------------- R0 fp32 VALU cell kernel (step 0 + ws fallback) ----------------
#define BT   64
#define JT   8
#define RT   32
#define KC   64
#define NT   256
#define NCHUNK 16
#define XSs  68
#define SMs  52
#define GBs  33

__global__ __launch_bounds__(NT) void lstm_cell_kernel(
    const float* __restrict__ Xbig0, const float* __restrict__ Wbig0,
    const float* __restrict__ Xbig1, const float* __restrict__ Wbig1,
    const float* __restrict__ Xsm0p, int K0,
    const float* __restrict__ Xsm1p, int K1,
    const float* __restrict__ Wsmall,
    const float* __restrict__ bih, const float* __restrict__ bhh,
    const float* __restrict__ cprev, float* __restrict__ cnew,
    const float* __restrict__ mask,
    float* __restrict__ hnew,
    const float* __restrict__ Wfc, const float* __restrict__ bfc,
    float* __restrict__ outp, int initOut)
{
    __shared__ float Xs[BT][XSs];
    __shared__ float Ws[RT][XSs];
    __shared__ float gbuf[BT][GBs];
    __shared__ float hbuf[BT][JT];
    __shared__ float Xsm[BT][SMs];
    __shared__ float Wsm[RT][SMs];

    const int tid = threadIdx.x;
    const int j0  = blockIdx.x * JT;
    const int b0  = blockIdx.y * BT;
    const int jp  = tid & 15;
    const int bq  = tid >> 4;

    auto GROW = [&](int r) { return ((r >> 3) * Hd + j0 + (r & 7)); };

    float acc[4][2];
    #pragma unroll
    for (int i = 0; i < 4; ++i) { acc[i][0] = 0.f; acc[i][1] = 0.f; }

    if (initOut && blockIdx.x == 0 && blockIdx.y == 0) {
        for (int i = tid; i < Bb * 3; i += NT) outp[i] = bfc[i % 3];
    }

    for (int seg = 0; seg < 2; ++seg) {
        const float* __restrict__ Xg = (seg == 0) ? Xbig0 : Xbig1;
        const float* __restrict__ Wg = (seg == 0) ? Wbig0 : Wbig1;
        if (Xg == nullptr) continue;

        float4 xr[4], wr[2];
        #pragma unroll
        for (int p = 0; p < 4; ++p) {
            int fi = p * NT + tid; int bloc = fi >> 4; int kq = fi & 15;
            xr[p] = *(const float4*)(Xg + (size_t)(b0 + bloc) * Hd + kq * 4);
        }
        #pragma unroll
        for (int p = 0; p < 2; ++p) {
            int fi = p * NT + tid; int r = fi >> 4; int kq = fi & 15;
            wr[p] = *(const float4*)(Wg + (size_t)GROW(r) * Hd + kq * 4);
        }
        #pragma unroll
        for (int p = 0; p < 4; ++p) { int fi = p * NT + tid; *(float4*)&Xs[fi >> 4][(fi & 15) * 4] = xr[p]; }
        #pragma unroll
        for (int p = 0; p < 2; ++p) { int fi = p * NT + tid; *(float4*)&Ws[fi >> 4][(fi & 15) * 4] = wr[p]; }
        __syncthreads();

        for (int kc = 0; kc < NCHUNK; ++kc) {
            const bool more = (kc + 1) < NCHUNK;
            if (more) {
                const int k0n = (kc + 1) * KC;
                #pragma unroll
                for (int p = 0; p < 4; ++p) {
                    int fi = p * NT + tid; int bloc = fi >> 4; int kq = fi & 15;
                    xr[p] = *(const float4*)(Xg + (size_t)(b0 + bloc) * Hd + k0n + kq * 4);
                }
                #pragma unroll
                for (int p = 0; p < 2; ++p) {
                    int fi = p * NT + tid; int r = fi >> 4; int kq = fi & 15;
                    wr[p] = *(const float4*)(Wg + (size_t)GROW(r) * Hd + k0n + kq * 4);
                }
            }
            #pragma unroll 4
            for (int kk = 0; kk < KC; kk += 4) {
                float4 w0 = *(const float4*)&Ws[jp][kk];
                float4 w1 = *(const float4*)&Ws[jp + 16][kk];
                #pragma unroll
                for (int bb = 0; bb < 4; ++bb) {
                    float4 xvv = *(const float4*)&Xs[bq + 16 * bb][kk];
                    acc[bb][0] += xvv.x * w0.x + xvv.y * w0.y + xvv.z * w0.z + xvv.w * w0.w;
                    acc[bb][1] += xvv.x * w1.x + xvv.y * w1.y + xvv.z * w1.z + xvv.w * w1.w;
                }
            }
            __syncthreads();
            if (more) {
                #pragma unroll
                for (int p = 0; p < 4; ++p) { int fi = p * NT + tid; *(float4*)&Xs[fi >> 4][(fi & 15) * 4] = xr[p]; }
                #pragma unroll
                for (int p = 0; p < 2; ++p) { int fi = p * NT + tid; *(float4*)&Ws[fi >> 4][(fi & 15) * 4] = wr[p]; }
                __syncthreads();
            }
        }
    }

    if (Wsmall) {
        const int Kt = K0 + K1;
        for (int i = tid; i < BT * Kt; i += NT) {
            int bloc = i / Kt, k = i % Kt;
            Xsm[bloc][k] = (k < K0) ? Xsm0p[(size_t)(b0 + bloc) * K0 + k]
                                    : Xsm1p[(size_t)(b0 + bloc) * K1 + (k - K0)];
        }
        for (int i = tid; i < RT * Kt; i += NT) {
            int r = i / Kt, k = i % Kt;
            Wsm[r][k] = Wsmall[(size_t)GROW(r) * Kt + k];
        }
        __syncthreads();
        for (int k = 0; k < Kt; ++k) {
            float w0 = Wsm[jp][k], w1 = Wsm[jp + 16][k];
            #pragma unroll
            for (int bb = 0; bb < 4; ++bb) {
                float xvv = Xsm[bq + 16 * bb][k];
                acc[bb][0] += xvv * w0;
                acc[bb][1] += xvv * w1;
            }
        }
    }

    __syncthreads();
    #pragma unroll
    for (int bb = 0; bb < 4; ++bb) {
        gbuf[bq + 16 * bb][jp]      = acc[bb][0];
        gbuf[bq + 16 * bb][jp + 16] = acc[bb][1];
    }
    __syncthreads();

    for (int p = tid; p < BT * JT; p += NT) {
        int bloc = p & (BT - 1);
        int j    = p >> 6;
        int bg   = b0 + bloc;
        int jc   = j0 + j;
        float gi = gbuf[bloc][j]      + bih[jc]          + bhh[jc];
        float gf = gbuf[bloc][8 + j]  + bih[Hd + jc]     + bhh[Hd + jc];
        float gg = gbuf[bloc][16 + j] + bih[2 * Hd + jc] + bhh[2 * Hd + jc];
        float go = gbuf[bloc][24 + j] + bih[3 * Hd + jc] + bhh[3 * Hd + jc];
        float cp = cprev[(size_t)bg * Hd + jc];
        float cn = sigm(gf) * cp + sigm(gi) * tanhf(gg);
        float hv = sigm(go) * tanhf(cn);
        if (mask) hv *= mask[(size_t)bg * Hd + jc];
        cnew[(size_t)bg * Hd + jc] = cn;
        hnew[(size_t)bg * Hd + jc] = hv;
        hbuf[bloc][j] = hv;
    }

    if (Wfc) {
        __syncthreads();
        if (tid < BT) {
            int bg = b0 + tid;
            #pragma unroll
            for (int m = 0; m < 3; ++m) {
                float s = 0.f;
                #pragma unroll
                for (int j = 0; j < JT; ++j) s += hbuf[tid][j] * Wfc[m * Hd + j0 + j];
                atomicAdd(&outp[bg * 3 + m], s);
            }
        }
    }
}

// ---------------- launch ----------------
extern "C" void kernel_launch(void* const* d_in, const int* in_sizes, int n_in,
                              void* d_out, int out_size, void* d_ws, size_t ws_size,
                              hipStream_t stream)
{
    (void)in_sizes; (void)n_in; (void)out_size;
    const float* cond   = (const float*)d_in[0];
    const float* noise  = (const float*)d_in[1];
    const float* h_init = (const float*)d_in[2];
    const float* c_init = (const float*)d_in[3];
    const float* dmask  = (const float*)d_in[4];
    const float* Wih0   = (const float*)d_in[5];
    const float* Whh0   = (const float*)d_in[6];
    const float* bih0   = (const float*)d_in[7];
    const float* bhh0   = (const float*)d_in[8];
    const float* Wih1   = (const float*)d_in[9];
    const float* Whh1   = (const float*)d_in[10];
    const float* bih1   = (const float*)d_in[11];
    const float* bhh1   = (const float*)d_in[12];
    const float* Wih2   = (const float*)d_in[13];
    const float* Whh2   = (const float*)d_in[14];
    const float* bih2   = (const float*)d_in[15];
    const float* bhh2   = (const float*)d_in[16];
    const float* Wfc    = (const float*)d_in[17];
    const float* bfc    = (const float*)d_in[18];
    float* out = (float*)d_out;

    char* wsb = (char*)d_ws;
    size_t off = 0;
    auto alloc = [&](size_t bytes) { size_t o = off; off += (bytes + 255) & ~(size_t)255; return o; };

    const size_t WBIG = (size_t)4 * Hd * Hd * 2;     // 4096x1024 bf16
    const size_t S    = (size_t)Bb * Hd;
    const size_t HBP  = S * 2 * PPAR;                // bf16 h history, PPAR parities
    const size_t HF   = S * 4;                       // fp32

    size_t o_w1 = alloc(WBIG);                        // Whh1 bf16
    size_t o_w2 = alloc(WBIG);                        // Wih2 bf16
    size_t o_w3 = alloc(WBIG);                        // Whh2 bf16
    size_t o_wsm = alloc((size_t)4 * Hd * 32 * 2);    // Wih1 padded bf16
    size_t o_h1h = alloc(HBP), o_h1l = alloc(HBP);
    size_t o_h2h = alloc(HBP), o_h2l = alloc(HBP);
    size_t o_c1 = alloc(HF), o_c2 = alloc(HF);
    size_t o_f1 = alloc(HF), o_f2 = alloc(HF);
    off = (off + 4095) & ~(size_t)4095;
    size_t o_bar = alloc(4096);
    const size_t needed = off;

    if (ws_size < needed) {
        // -------- fallback: full R0 fp32 path --------
        float* ws = (float*)d_ws;
        float* h1a = ws;         float* h1b = ws + S;
        float* h2a = ws + 2 * S; float* h2b = ws + 3 * S;
        float* c1  = ws + 4 * S; float* c2  = ws + 5 * S;
        dim3 grid(Hd / JT, Bb / BT);
        dim3 blk(NT);
        lstm_cell_kernel<<<grid, blk, 0, stream>>>(
            h_init, Whh0, nullptr, nullptr, cond, Cd, noise, Nd, Wih0,
            bih0, bhh0, c_init, c1, dmask, h1a, nullptr, bfc, out, 1);
        lstm_cell_kernel<<<grid, blk, 0, stream>>>(
            h1a, Wih2, h_init, Whh2, nullptr, 0, nullptr, 0, nullptr,
            bih2, bhh2, c_init, c2, nullptr, h2a, Wfc, bfc, out, 0);
        const float* h1prev = h1a; const float* h2prev = h2a;
        for (int t = 1; t < Ld; ++t) {
            float* h1cur = (t & 1) ? h1b : h1a;
            float* h2cur = (t & 1) ? h2b : h2a;
            lstm_cell_kernel<<<grid, blk, 0, stream>>>(
                h1prev, Whh1, nullptr, nullptr,
                cond + (size_t)t * Bb * Cd, Cd, out + (size_t)(t - 1) * Bb * Md, Md, Wih1,
                bih1, bhh1, c1, c1, dmask + (size_t)t * Bb * Hd, h1cur,
                nullptr, bfc, out + (size_t)t * Bb * Md, 1);
            lstm_cell_kernel<<<grid, blk, 0, stream>>>(
                h1cur, Wih2, h2prev, Whh2, nullptr, 0, nullptr, 0, nullptr,
                bih2, bhh2, c2, c2, nullptr, h2cur, Wfc, bfc, out + (size_t)t * Bb * Md, 0);
            h1prev = h1cur; h2prev = h2cur;
        }
        return;
    }

    auto U16 = [&](size_t o) { return (unsigned short*)(wsb + o); };
    auto F32 = [&](size_t o) { return (float*)(wsb + o); };

    // 0) zero the pair-barrier counters
    hipMemsetAsync(wsb + o_bar, 0, 1024, stream);

    // 1) weights -> bf16 (single level; activations carry hi/lo)
    const int NW = 4 * Hd * Hd;
    cast_kernel<<<2048, 256, 0, stream>>>(Whh1, U16(o_w1), NW);
    cast_kernel<<<2048, 256, 0, stream>>>(Wih2, U16(o_w2), NW);
    cast_kernel<<<2048, 256, 0, stream>>>(Whh2, U16(o_w3), NW);
    cast_pad_kernel<<<512, 256, 0, stream>>>(Wih1, U16(o_wsm), 4 * Hd, Cd + Md, 32);

    // 2) step 0 via the proven fp32 kernel (writes h parity 0, k-blocked)
    {
        dim3 grid(Hd / JT, Bb / BT);
        dim3 blk(NT);
        lstm_cell_kernel<<<grid, blk, 0, stream>>>(
            h_init, Whh0, nullptr, nullptr, cond, Cd, noise, Nd, Wih0,
            bih0, bhh0, c_init, F32(o_c1), dmask, F32(o_f1), nullptr, bfc, out, 1);
        lstm_cell_kernel<<<grid, blk, 0, stream>>>(
            F32(o_f1), Wih2, h_init, Whh2, nullptr, 0, nullptr, 0, nullptr,
            bih2, bhh2, c_init, F32(o_c2), nullptr, F32(o_f2), Wfc, bfc, out, 0);
        split_blocked_kernel<<<512, 256, 0, stream>>>(F32(o_f1), U16(o_h1h), U16(o_h1l));
        split_blocked_kernel<<<512, 256, 0, stream>>>(F32(o_f2), U16(o_h2h), U16(o_h2l));
    }

    // 3) steps 1..255 in ONE persistent kernel (256 WGs, 4 independent pair-groups)
    lstm_persistent<<<256, 512, 0, stream>>>(
        U16(o_w1), U16(o_w2), U16(o_w3), U16(o_wsm),
        cond, dmask, bih1, bhh1, bih2, bhh2,
        F32(o_c1), F32(o_c2),
        U16(o_h1h), U16(o_h1l), U16(o_h2h), U16(o_h2l),
        Wfc, bfc, out, (unsigned*)(wsb + o_bar));
}

// Round 7
// 7961.324 us; speedup vs baseline: 1.4459x; 1.0094x over previous
//
#include <hip/hip_runtime.h>
#include <math.h>

// ---------------- problem constants ----------------
#define Bb   128
#define Hd   1024
#define Ld   256
#define Cd   20
#define Nd   30
#define Md   3
#define PPAR 64     // h-history depth (unique-address coherence window)

using bfrag = __attribute__((ext_vector_type(8)))  short;  // 8 bf16 (4 VGPRs)
using f16v  = __attribute__((ext_vector_type(16))) float;  // 32x32 C/D

union Pack8 { bfrag v; unsigned short u[8]; };

__device__ __forceinline__ float sigm(float x) { return 1.0f / (1.0f + expf(-x)); }

__device__ __forceinline__ unsigned short bf_rne(float x) {
    unsigned u = __float_as_uint(x);
    unsigned r = (u + 0x7fffu + ((u >> 16) & 1u)) >> 16;
    return (unsigned short)r;
}
__device__ __forceinline__ float bf_f(unsigned short h) {
    return __uint_as_float(((unsigned)h) << 16);
}

#define MFMA(a,b,c) __builtin_amdgcn_mfma_f32_32x32x16_bf16((a),(b),(c),0,0,0)

// async global->LDS, 16B/lane, PLAIN (L2-allocating).
__device__ __forceinline__ void gld_lds16(const void* g, void* s) {
    __builtin_amdgcn_global_load_lds((const __attribute__((address_space(1))) void*)g,
                                     (__attribute__((address_space(3))) void*)s, 16, 0, 0);
}
// s_waitcnt imm: vmcnt[3:0] | exp<<4 (7=off) | lgkm<<8 (15=off)
#define WAIT_VM(n)  __builtin_amdgcn_s_waitcnt(0x0F70 | (n))
#define WAIT_LGKM() __builtin_amdgcn_s_waitcnt(0xC07F)

// ---------------- preamble kernels ----------------
__global__ void cast_kernel(const float* __restrict__ src,
                            unsigned short* __restrict__ dst, int n)
{
    for (int i = blockIdx.x * blockDim.x + threadIdx.x; i < n; i += gridDim.x * blockDim.x)
        dst[i] = bf_rne(src[i]);
}

__global__ void cast_pad_kernel(const float* __restrict__ src,
                                unsigned short* __restrict__ dst,
                                int rows, int K, int Kp)
{
    int n = rows * Kp;
    for (int i = blockIdx.x * blockDim.x + threadIdx.x; i < n; i += gridDim.x * blockDim.x) {
        int r = i / Kp, k = i - r * Kp;
        dst[i] = bf_rne((k < K) ? src[r * K + k] : 0.0f);
    }
}

// fp32 flat [b][j] -> bf16 hi/lo in k-blocked layout [j>>3][b][j&7]
__global__ void split_blocked_kernel(const float* __restrict__ src,
                                     unsigned short* __restrict__ hi,
                                     unsigned short* __restrict__ lo)
{
    int i = blockIdx.x * blockDim.x + threadIdx.x;
    if (i < Bb * Hd) {
        int b = i / Hd, j = i % Hd;
        float x = src[i];
        unsigned short h = bf_rne(x);
        size_t d = (size_t)((j >> 3) * Bb + b) * 8 + (j & 7);
        hi[d] = h;
        lo[d] = bf_rne(x - bf_f(h));
    }
}

// ---------------- persistent fused LSTM, W-in-VGPR (forced @ 2 waves/EU) ----------------
// Grid 256 x 512 (8 waves), 1 WG/CU. mtile=(bid&7)>>1 (XCD-pair owns batch
// quarter), jtile=((bid&1)<<5)+(bid>>3). Tile M=32 x N=64 (4 gates x 16 j).
// amdgpu_waves_per_eu(2,2): VGPR budget 256/wave so the 192 asm-pinned W frags
// (W1/W2/W3, per-wave 128-k slice) stay RESIDENT (R5 spilled them at the
// default-occupancy 128-reg target -> 9 GB of scratch reloads).
// A staged via coalesced global_load_lds from k-blocked h layout.
__global__ __attribute__((amdgpu_flat_work_group_size(512, 512)))
           __attribute__((amdgpu_waves_per_eu(2, 2)))
void lstm_persistent(
    const unsigned short* __restrict__ W1, const unsigned short* __restrict__ W2,
    const unsigned short* __restrict__ W3, const unsigned short* __restrict__ Wsm,
    const float* __restrict__ cond, const float* __restrict__ dmask,
    const float* __restrict__ bih1, const float* __restrict__ bhh1,
    const float* __restrict__ bih2, const float* __restrict__ bhh2,
    float* __restrict__ c1, float* __restrict__ c2,
    unsigned short* __restrict__ h1h, unsigned short* __restrict__ h1l,
    unsigned short* __restrict__ h2h, unsigned short* __restrict__ h2l,
    const float* __restrict__ Wfc, const float* __restrict__ bfc,
    float* __restrict__ out, unsigned* __restrict__ barpage)
{
    __shared__ union {
        unsigned short A[2][32768];                        // [hi/lo][wave*4096 + rb*256 + ml*8]
        struct { float part[8][32][65]; float hbuf[32][16]; } r;
    } U;

    const int bid   = blockIdx.x;
    const int mtile = (bid & 7) >> 1;                      // XCD-pair id
    const int jtile = ((bid & 1) << 5) + (bid >> 3);
    const int j0 = jtile * 16, m0 = mtile * 32;

    const int tid  = threadIdx.x;
    const int wave = tid >> 6;
    const int lane = tid & 63;
    const int ml   = lane & 31;
    const int q    = lane >> 5;
    const size_t S = (size_t)Bb * Hd;

    unsigned* barcnt = barpage + mtile * 64;               // 256B-separated counters
    unsigned bar_target = 0;

    const int g0 = ml >> 4, jj0 = ml & 15;
    const size_t row0 = (size_t)(g0 * Hd + j0 + jj0);      // C0 cols: gates 0/1
    const size_t row1 = (size_t)((g0 + 2) * Hd + j0 + jj0);// C1 cols: gates 2/3

    // ---- pin W frags in VGPRs: per wave, k-slice [wave*128, wave*128+128) ----
    bfrag w1f[8][2], w2f[8][2], w3f[8][2];
    #pragma unroll
    for (int i = 0; i < 8; ++i) {
        const int k = wave * 128 + 16 * i + 8 * q;
        w1f[i][0] = *(const bfrag*)(W1 + row0 * Hd + k);
        w1f[i][1] = *(const bfrag*)(W1 + row1 * Hd + k);
        w2f[i][0] = *(const bfrag*)(W2 + row0 * Hd + k);
        w2f[i][1] = *(const bfrag*)(W2 + row1 * Hd + k);
        w3f[i][0] = *(const bfrag*)(W3 + row0 * Hd + k);
        w3f[i][1] = *(const bfrag*)(W3 + row1 * Hd + k);
    }
    // force residency: values become asm-defined -> no rematerialization
    #pragma unroll
    for (int i = 0; i < 8; ++i) {
        asm volatile("" : "+v"(w1f[i][0]), "+v"(w1f[i][1]),
                          "+v"(w2f[i][0]), "+v"(w2f[i][1]),
                          "+v"(w3f[i][0]), "+v"(w3f[i][1]));
    }

    auto pair_bar = [&]() {
        bar_target += 64;
        __syncthreads();   // drains vmcnt -> scoped stores done before arrival
        if (tid == 0) {
            __hip_atomic_fetch_add(barcnt, 1u, __ATOMIC_RELAXED, __HIP_MEMORY_SCOPE_AGENT);
            while (__hip_atomic_load(barcnt, __ATOMIC_RELAXED, __HIP_MEMORY_SCOPE_AGENT) < bar_target)
                __builtin_amdgcn_s_sleep(2);
        }
        __syncthreads();
    };

    // stage issue i: two k8-blocks (lanes 0-31 -> block 2i, 32-63 -> 2i+1 of this
    // wave's 16-block slice), fully coalesced (2x 512B contiguous), hi + lo.
    auto stage_issue = [&](const unsigned short* Ah, const unsigned short* Al, int i) {
        const size_t g = (size_t)((wave * 16 + 2 * i + q) * Bb + m0 + ml) * 8;
        const int base = wave * 4096 + i * 512;            // halfwords, wave-uniform
        gld_lds16(Ah + g, &U.A[0][base]);
        gld_lds16(Al + g, &U.A[1][base]);
    };

#define KSTEP(i, wc, WF) { \
        WAIT_VM(wc); \
        const int hw = wave * 4096 + (2 * (i) + q) * 256 + ml * 8; \
        bfrag ah = *(const bfrag*)&U.A[0][hw]; \
        bfrag al = *(const bfrag*)&U.A[1][hw]; \
        C0 = MFMA(ah, WF[i][0], C0); \
        C1 = MFMA(ah, WF[i][1], C1); \
        C0 = MFMA(al, WF[i][0], C0); \
        C1 = MFMA(al, WF[i][1], C1); \
    }
#define RUN8(WF) \
    KSTEP(0,14,WF) KSTEP(1,12,WF) KSTEP(2,10,WF) KSTEP(3,8,WF) \
    KSTEP(4, 6,WF) KSTEP(5, 4,WF) KSTEP(6, 2,WF) KSTEP(7,0,WF)

    auto dump_part = [&](const f16v& C0, const f16v& C1) {
        #pragma unroll
        for (int r = 0; r < 16; ++r) {
            const int mrow = (r & 3) + 8 * (r >> 2) + 4 * q;
            U.r.part[wave][mrow][ml]      = C0[r];
            U.r.part[wave][mrow][32 + ml] = C1[r];
        }
    };

    #pragma clang loop unroll(disable)
    for (int t = 1; t < Ld; ++t) {
        const int cur = t & (PPAR - 1), prv = (t - 1) & (PPAR - 1);
        float* outp_t = out + (size_t)t * Bb * Md;
        const float* outp_p = out + (size_t)(t - 1) * Bb * Md;

        // ================= phase A : cell1 =================
        {
            const unsigned short* Ah = h1h + (size_t)prv * S;
            const unsigned short* Al = h1l + (size_t)prv * S;
            #pragma unroll
            for (int i = 0; i < 8; ++i) stage_issue(Ah, Al, i);
            f16v C0, C1;
            #pragma unroll
            for (int r = 0; r < 16; ++r) { C0[r] = 0.f; C1[r] = 0.f; }
            RUN8(w1f);
            // out[t] init (one WG per pair; precedes FC atomics via pair_bar)
            if (jtile == 0 && tid < 32 * Md) {
                const int r = tid / Md, m = tid % Md;
                __hip_atomic_store(&outp_t[(m0 + r) * Md + m], bfc[m],
                                   __ATOMIC_RELAXED, __HIP_MEMORY_SCOPE_AGENT);
            }
            // small segment (wave 0): cat(cond[t][20], out[t-1][3]) padded to K=32
            if (wave == 0) {
                const float* crow = cond + (size_t)t * Bb * Cd + (m0 + ml) * Cd;
                const float* orow = outp_p + (m0 + ml) * Md;
                float xv[2][8];
                #pragma unroll
                for (int j = 0; j < 8; ++j) { xv[0][j] = 0.f; xv[1][j] = 0.f; }
                if (q == 0) {
                    #pragma unroll
                    for (int j = 0; j < 8; ++j) xv[0][j] = crow[j];
                    xv[1][0] = crow[16]; xv[1][1] = crow[17];
                    xv[1][2] = crow[18]; xv[1][3] = crow[19];
                    xv[1][4] = __hip_atomic_load((float*)&orow[0], __ATOMIC_RELAXED, __HIP_MEMORY_SCOPE_AGENT);
                    xv[1][5] = __hip_atomic_load((float*)&orow[1], __ATOMIC_RELAXED, __HIP_MEMORY_SCOPE_AGENT);
                    xv[1][6] = __hip_atomic_load((float*)&orow[2], __ATOMIC_RELAXED, __HIP_MEMORY_SCOPE_AGENT);
                } else {
                    #pragma unroll
                    for (int j = 0; j < 8; ++j) xv[0][j] = crow[8 + j];
                }
                #pragma unroll
                for (int ch = 0; ch < 2; ++ch) {
                    Pack8 ah, al;
                    #pragma unroll
                    for (int j = 0; j < 8; ++j) {
                        unsigned short h = bf_rne(xv[ch][j]);
                        ah.u[j] = h;
                        al.u[j] = bf_rne(xv[ch][j] - bf_f(h));
                    }
                    const int kk = ch * 16 + 8 * q;
                    bfrag b0 = *(const bfrag*)(Wsm + row0 * 32 + kk);
                    bfrag b1 = *(const bfrag*)(Wsm + row1 * 32 + kk);
                    C0 = MFMA(ah.v, b0, C0);
                    C1 = MFMA(ah.v, b1, C1);
                    C0 = MFMA(al.v, b0, C0);
                    C1 = MFMA(al.v, b1, C1);
                }
            }
            __syncthreads();
            dump_part(C0, C1);
            __syncthreads();
            if (tid < 256) {
                const int m = tid >> 3, j2 = (tid & 7) * 2;
                const int b = m0 + m, jc = j0 + j2;
                const size_t idx = (size_t)b * Hd + jc;
                const size_t bidx = (size_t)((jc >> 3) * Bb + b) * 8 + (jc & 7);
                float g[4][2];
                #pragma unroll
                for (int gg = 0; gg < 4; ++gg) {
                    #pragma unroll
                    for (int e = 0; e < 2; ++e) {
                        float s = 0.f;
                        #pragma unroll
                        for (int w = 0; w < 8; ++w) s += U.r.part[w][m][gg * 16 + j2 + e];
                        const int n = gg * Hd + jc + e;
                        g[gg][e] = s + bih1[n] + bhh1[n];
                    }
                }
                float2 cp = *(const float2*)&c1[idx];
                float2 mv = *(const float2*)&dmask[(size_t)t * S + idx];
                float cn0 = sigm(g[1][0]) * cp.x + sigm(g[0][0]) * tanhf(g[2][0]);
                float cn1 = sigm(g[1][1]) * cp.y + sigm(g[0][1]) * tanhf(g[2][1]);
                float hv0 = sigm(g[3][0]) * tanhf(cn0) * mv.x;
                float hv1 = sigm(g[3][1]) * tanhf(cn1) * mv.y;
                *(float2*)&c1[idx] = make_float2(cn0, cn1);
                unsigned short h0 = bf_rne(hv0), h1_ = bf_rne(hv1);
                unsigned hp = (unsigned)h0 | ((unsigned)h1_ << 16);
                unsigned lp = (unsigned)bf_rne(hv0 - bf_f(h0)) | ((unsigned)bf_rne(hv1 - bf_f(h1_)) << 16);
                __hip_atomic_store((unsigned*)&h1h[(size_t)cur * S + bidx], hp, __ATOMIC_RELAXED, __HIP_MEMORY_SCOPE_AGENT);
                __hip_atomic_store((unsigned*)&h1l[(size_t)cur * S + bidx], lp, __ATOMIC_RELAXED, __HIP_MEMORY_SCOPE_AGENT);
            }
            pair_bar();
        }

        // ================= phase B : cell2 =================
        {
            const unsigned short* A2h = h1h + (size_t)cur * S;
            const unsigned short* A2l = h1l + (size_t)cur * S;
            const unsigned short* A3h = h2h + (size_t)prv * S;
            const unsigned short* A3l = h2l + (size_t)prv * S;
            f16v C0, C1;
            #pragma unroll
            for (int r = 0; r < 16; ++r) { C0[r] = 0.f; C1[r] = 0.f; }
            #pragma unroll
            for (int i = 0; i < 8; ++i) stage_issue(A2h, A2l, i);
            RUN8(w2f);
            WAIT_LGKM();                 // last ds_reads done before overwrite
            #pragma unroll
            for (int i = 0; i < 8; ++i) stage_issue(A3h, A3l, i);
            RUN8(w3f);
            __syncthreads();
            dump_part(C0, C1);
            __syncthreads();
            if (tid < 256) {
                const int m = tid >> 3, j2 = (tid & 7) * 2;
                const int b = m0 + m, jc = j0 + j2;
                const size_t idx = (size_t)b * Hd + jc;
                const size_t bidx = (size_t)((jc >> 3) * Bb + b) * 8 + (jc & 7);
                float g[4][2];
                #pragma unroll
                for (int gg = 0; gg < 4; ++gg) {
                    #pragma unroll
                    for (int e = 0; e < 2; ++e) {
                        float s = 0.f;
                        #pragma unroll
                        for (int w = 0; w < 8; ++w) s += U.r.part[w][m][gg * 16 + j2 + e];
                        const int n = gg * Hd + jc + e;
                        g[gg][e] = s + bih2[n] + bhh2[n];
                    }
                }
                float2 cp = *(const float2*)&c2[idx];
                float cn0 = sigm(g[1][0]) * cp.x + sigm(g[0][0]) * tanhf(g[2][0]);
                float cn1 = sigm(g[1][1]) * cp.y + sigm(g[0][1]) * tanhf(g[2][1]);
                float hv0 = sigm(g[3][0]) * tanhf(cn0);
                float hv1 = sigm(g[3][1]) * tanhf(cn1);
                *(float2*)&c2[idx] = make_float2(cn0, cn1);
                U.r.hbuf[m][j2]     = hv0;
                U.r.hbuf[m][j2 + 1] = hv1;
                unsigned short h0 = bf_rne(hv0), h1_ = bf_rne(hv1);
                unsigned hp = (unsigned)h0 | ((unsigned)h1_ << 16);
                unsigned lp = (unsigned)bf_rne(hv0 - bf_f(h0)) | ((unsigned)bf_rne(hv1 - bf_f(h1_)) << 16);
                __hip_atomic_store((unsigned*)&h2h[(size_t)cur * S + bidx], hp, __ATOMIC_RELAXED, __HIP_MEMORY_SCOPE_AGENT);
                __hip_atomic_store((unsigned*)&h2l[(size_t)cur * S + bidx], lp, __ATOMIC_RELAXED, __HIP_MEMORY_SCOPE_AGENT);
            }
            __syncthreads();
            if (tid < 32) {
                const int b = m0 + tid;
                #pragma unroll
                for (int mm = 0; mm < Md; ++mm) {
                    float s = 0.0f;
                    #pragma unroll
                    for (int jj = 0; jj < 16; ++jj) s += U.r.hbuf[tid][jj] * Wfc[mm * Hd + j0 + jj];
                    atomicAdd(&outp_t[b * Md + mm], s);
                }
            }
            pair_bar();
        }
    }
#undef KSTEP
#undef RUN8
}

// ---------------- R0 fp32 VALU cell kernel (step 0 + ws fallback) ----------------
#define BT   64
#define JT   8
#define RT   32
#define KC   64
#define NT   256
#define NCHUNK 16
#define XSs  68
#define SMs  52
#define GBs  33

__global__ __launch_bounds__(NT) void lstm_cell_kernel(
    const float* __restrict__ Xbig0, const float* __restrict__ Wbig0,
    const float* __restrict__ Xbig1, const float* __restrict__ Wbig1,
    const float* __restrict__ Xsm0p, int K0,
    const float* __restrict__ Xsm1p, int K1,
    const float* __restrict__ Wsmall,
    const float* __restrict__ bih, const float* __restrict__ bhh,
    const float* __restrict__ cprev, float* __restrict__ cnew,
    const float* __restrict__ mask,
    float* __restrict__ hnew,
    const float* __restrict__ Wfc, const float* __restrict__ bfc,
    float* __restrict__ outp, int initOut)
{
    __shared__ float Xs[BT][XSs];
    __shared__ float Ws[RT][XSs];
    __shared__ float gbuf[BT][GBs];
    __shared__ float hbuf[BT][JT];
    __shared__ float Xsm[BT][SMs];
    __shared__ float Wsm[RT][SMs];

    const int tid = threadIdx.x;
    const int j0  = blockIdx.x * JT;
    const int b0  = blockIdx.y * BT;
    const int jp  = tid & 15;
    const int bq  = tid >> 4;

    auto GROW = [&](int r) { return ((r >> 3) * Hd + j0 + (r & 7)); };

    float acc[4][2];
    #pragma unroll
    for (int i = 0; i < 4; ++i) { acc[i][0] = 0.f; acc[i][1] = 0.f; }

    if (initOut && blockIdx.x == 0 && blockIdx.y == 0) {
        for (int i = tid; i < Bb * 3; i += NT) outp[i] = bfc[i % 3];
    }

    for (int seg = 0; seg < 2; ++seg) {
        const float* __restrict__ Xg = (seg == 0) ? Xbig0 : Xbig1;
        const float* __restrict__ Wg = (seg == 0) ? Wbig0 : Wbig1;
        if (Xg == nullptr) continue;

        float4 xr[4], wr[2];
        #pragma unroll
        for (int p = 0; p < 4; ++p) {
            int fi = p * NT + tid; int bloc = fi >> 4; int kq = fi & 15;
            xr[p] = *(const float4*)(Xg + (size_t)(b0 + bloc) * Hd + kq * 4);
        }
        #pragma unroll
        for (int p = 0; p < 2; ++p) {
            int fi = p * NT + tid; int r = fi >> 4; int kq = fi & 15;
            wr[p] = *(const float4*)(Wg + (size_t)GROW(r) * Hd + kq * 4);
        }
        #pragma unroll
        for (int p = 0; p < 4; ++p) { int fi = p * NT + tid; *(float4*)&Xs[fi >> 4][(fi & 15) * 4] = xr[p]; }
        #pragma unroll
        for (int p = 0; p < 2; ++p) { int fi = p * NT + tid; *(float4*)&Ws[fi >> 4][(fi & 15) * 4] = wr[p]; }
        __syncthreads();

        for (int kc = 0; kc < NCHUNK; ++kc) {
            const bool more = (kc + 1) < NCHUNK;
            if (more) {
                const int k0n = (kc + 1) * KC;
                #pragma unroll
                for (int p = 0; p < 4; ++p) {
                    int fi = p * NT + tid; int bloc = fi >> 4; int kq = fi & 15;
                    xr[p] = *(const float4*)(Xg + (size_t)(b0 + bloc) * Hd + k0n + kq * 4);
                }
                #pragma unroll
                for (int p = 0; p < 2; ++p) {
                    int fi = p * NT + tid; int r = fi >> 4; int kq = fi & 15;
                    wr[p] = *(const float4*)(Wg + (size_t)GROW(r) * Hd + k0n + kq * 4);
                }
            }
            #pragma unroll 4
            for (int kk = 0; kk < KC; kk += 4) {
                float4 w0 = *(const float4*)&Ws[jp][kk];
                float4 w1 = *(const float4*)&Ws[jp + 16][kk];
                #pragma unroll
                for (int bb = 0; bb < 4; ++bb) {
                    float4 xvv = *(const float4*)&Xs[bq + 16 * bb][kk];
                    acc[bb][0] += xvv.x * w0.x + xvv.y * w0.y + xvv.z * w0.z + xvv.w * w0.w;
                    acc[bb][1] += xvv.x * w1.x + xvv.y * w1.y + xvv.z * w1.z + xvv.w * w1.w;
                }
            }
            __syncthreads();
            if (more) {
                #pragma unroll
                for (int p = 0; p < 4; ++p) { int fi = p * NT + tid; *(float4*)&Xs[fi >> 4][(fi & 15) * 4] = xr[p]; }
                #pragma unroll
                for (int p = 0; p < 2; ++p) { int fi = p * NT + tid; *(float4*)&Ws[fi >> 4][(fi & 15) * 4] = wr[p]; }
                __syncthreads();
            }
        }
    }

    if (Wsmall) {
        const int Kt = K0 + K1;
        for (int i = tid; i < BT * Kt; i += NT) {
            int bloc = i / Kt, k = i % Kt;
            Xsm[bloc][k] = (k < K0) ? Xsm0p[(size_t)(b0 + bloc) * K0 + k]
                                    : Xsm1p[(size_t)(b0 + bloc) * K1 + (k - K0)];
        }
        for (int i = tid; i < RT * Kt; i += NT) {
            int r = i / Kt, k = i % Kt;
            Wsm[r][k] = Wsmall[(size_t)GROW(r) * Kt + k];
        }
        __syncthreads();
        for (int k = 0; k < Kt; ++k) {
            float w0 = Wsm[jp][k], w1 = Wsm[jp + 16][k];
            #pragma unroll
            for (int bb = 0; bb < 4; ++bb) {
                float xvv = Xsm[bq + 16 * bb][k];
                acc[bb][0] += xvv * w0;
                acc[bb][1] += xvv * w1;
            }
        }
    }

    __syncthreads();
    #pragma unroll
    for (int bb = 0; bb < 4; ++bb) {
        gbuf[bq + 16 * bb][jp]      = acc[bb][0];
        gbuf[bq + 16 * bb][jp + 16] = acc[bb][1];
    }
    __syncthreads();

    for (int p = tid; p < BT * JT; p += NT) {
        int bloc = p & (BT - 1);
        int j    = p >> 6;
        int bg   = b0 + bloc;
        int jc   = j0 + j;
        float gi = gbuf[bloc][j]      + bih[jc]          + bhh[jc];
        float gf = gbuf[bloc][8 + j]  + bih[Hd + jc]     + bhh[Hd + jc];
        float gg = gbuf[bloc][16 + j] + bih[2 * Hd + jc] + bhh[2 * Hd + jc];
        float go = gbuf[bloc][24 + j] + bih[3 * Hd + jc] + bhh[3 * Hd + jc];
        float cp = cprev[(size_t)bg * Hd + jc];
        float cn = sigm(gf) * cp + sigm(gi) * tanhf(gg);
        float hv = sigm(go) * tanhf(cn);
        if (mask) hv *= mask[(size_t)bg * Hd + jc];
        cnew[(size_t)bg * Hd + jc] = cn;
        hnew[(size_t)bg * Hd + jc] = hv;
        hbuf[bloc][j] = hv;
    }

    if (Wfc) {
        __syncthreads();
        if (tid < BT) {
            int bg = b0 + tid;
            #pragma unroll
            for (int m = 0; m < 3; ++m) {
                float s = 0.f;
                #pragma unroll
                for (int j = 0; j < JT; ++j) s += hbuf[tid][j] * Wfc[m * Hd + j0 + j];
                atomicAdd(&outp[bg * 3 + m], s);
            }
        }
    }
}

// ---------------- launch ----------------
extern "C" void kernel_launch(void* const* d_in, const int* in_sizes, int n_in,
                              void* d_out, int out_size, void* d_ws, size_t ws_size,
                              hipStream_t stream)
{
    (void)in_sizes; (void)n_in; (void)out_size;
    const float* cond   = (const float*)d_in[0];
    const float* noise  = (const float*)d_in[1];
    const float* h_init = (const float*)d_in[2];
    const float* c_init = (const float*)d_in[3];
    const float* dmask  = (const float*)d_in[4];
    const float* Wih0   = (const float*)d_in[5];
    const float* Whh0   = (const float*)d_in[6];
    const float* bih0   = (const float*)d_in[7];
    const float* bhh0   = (const float*)d_in[8];
    const float* Wih1   = (const float*)d_in[9];
    const float* Whh1   = (const float*)d_in[10];
    const float* bih1   = (const float*)d_in[11];
    const float* bhh1   = (const float*)d_in[12];
    const float* Wih2   = (const float*)d_in[13];
    const float* Whh2   = (const float*)d_in[14];
    const float* bih2   = (const float*)d_in[15];
    const float* bhh2   = (const float*)d_in[16];
    const float* Wfc    = (const float*)d_in[17];
    const float* bfc    = (const float*)d_in[18];
    float* out = (float*)d_out;

    char* wsb = (char*)d_ws;
    size_t off = 0;
    auto alloc = [&](size_t bytes) { size_t o = off; off += (bytes + 255) & ~(size_t)255; return o; };

    const size_t WBIG = (size_t)4 * Hd * Hd * 2;     // 4096x1024 bf16
    const size_t S    = (size_t)Bb * Hd;
    const size_t HBP  = S * 2 * PPAR;                // bf16 h history, PPAR parities
    const size_t HF   = S * 4;                       // fp32

    size_t o_w1 = alloc(WBIG);                        // Whh1 bf16
    size_t o_w2 = alloc(WBIG);                        // Wih2 bf16
    size_t o_w3 = alloc(WBIG);                        // Whh2 bf16
    size_t o_wsm = alloc((size_t)4 * Hd * 32 * 2);    // Wih1 padded bf16
    size_t o_h1h = alloc(HBP), o_h1l = alloc(HBP);
    size_t o_h2h = alloc(HBP), o_h2l = alloc(HBP);
    size_t o_c1 = alloc(HF), o_c2 = alloc(HF);
    size_t o_f1 = alloc(HF), o_f2 = alloc(HF);
    off = (off + 4095) & ~(size_t)4095;
    size_t o_bar = alloc(4096);
    const size_t needed = off;

    if (ws_size < needed) {
        // -------- fallback: full R0 fp32 path --------
        float* ws = (float*)d_ws;
        float* h1a = ws;         float* h1b = ws + S;
        float* h2a = ws + 2 * S; float* h2b = ws + 3 * S;
        float* c1  = ws + 4 * S; float* c2  = ws + 5 * S;
        dim3 grid(Hd / JT, Bb / BT);
        dim3 blk(NT);
        lstm_cell_kernel<<<grid, blk, 0, stream>>>(
            h_init, Whh0, nullptr, nullptr, cond, Cd, noise, Nd, Wih0,
            bih0, bhh0, c_init, c1, dmask, h1a, nullptr, bfc, out, 1);
        lstm_cell_kernel<<<grid, blk, 0, stream>>>(
            h1a, Wih2, h_init, Whh2, nullptr, 0, nullptr, 0, nullptr,
            bih2, bhh2, c_init, c2, nullptr, h2a, Wfc, bfc, out, 0);
        const float* h1prev = h1a; const float* h2prev = h2a;
        for (int t = 1; t < Ld; ++t) {
            float* h1cur = (t & 1) ? h1b : h1a;
            float* h2cur = (t & 1) ? h2b : h2a;
            lstm_cell_kernel<<<grid, blk, 0, stream>>>(
                h1prev, Whh1, nullptr, nullptr,
                cond + (size_t)t * Bb * Cd, Cd, out + (size_t)(t - 1) * Bb * Md, Md, Wih1,
                bih1, bhh1, c1, c1, dmask + (size_t)t * Bb * Hd, h1cur,
                nullptr, bfc, out + (size_t)t * Bb * Md, 1);
            lstm_cell_kernel<<<grid, blk, 0, stream>>>(
                h1cur, Wih2, h2prev, Whh2, nullptr, 0, nullptr, 0, nullptr,
                bih2, bhh2, c2, c2, nullptr, h2cur, Wfc, bfc, out + (size_t)t * Bb * Md, 0);
            h1prev = h1cur; h2prev = h2cur;
        }
        return;
    }

    auto U16 = [&](size_t o) { return (unsigned short*)(wsb + o); };
    auto F32 = [&](size_t o) { return (float*)(wsb + o); };

    // 0) zero the pair-barrier counters
    hipMemsetAsync(wsb + o_bar, 0, 1024, stream);

    // 1) weights -> bf16 (single level; activations carry hi/lo)
    const int NW = 4 * Hd * Hd;
    cast_kernel<<<2048, 256, 0, stream>>>(Whh1, U16(o_w1), NW);
    cast_kernel<<<2048, 256, 0, stream>>>(Wih2, U16(o_w2), NW);
    cast_kernel<<<2048, 256, 0, stream>>>(Whh2, U16(o_w3), NW);
    cast_pad_kernel<<<512, 256, 0, stream>>>(Wih1, U16(o_wsm), 4 * Hd, Cd + Md, 32);

    // 2) step 0 via the proven fp32 kernel (writes h parity 0, k-blocked)
    {
        dim3 grid(Hd / JT, Bb / BT);
        dim3 blk(NT);
        lstm_cell_kernel<<<grid, blk, 0, stream>>>(
            h_init, Whh0, nullptr, nullptr, cond, Cd, noise, Nd, Wih0,
            bih0, bhh0, c_init, F32(o_c1), dmask, F32(o_f1), nullptr, bfc, out, 1);
        lstm_cell_kernel<<<grid, blk, 0, stream>>>(
            F32(o_f1), Wih2, h_init, Whh2, nullptr, 0, nullptr, 0, nullptr,
            bih2, bhh2, c_init, F32(o_c2), nullptr, F32(o_f2), Wfc, bfc, out, 0);
        split_blocked_kernel<<<512, 256, 0, stream>>>(F32(o_f1), U16(o_h1h), U16(o_h1l));
        split_blocked_kernel<<<512, 256, 0, stream>>>(F32(o_f2), U16(o_h2h), U16(o_h2l));
    }

    // 3) steps 1..255 in ONE persistent kernel (256 WGs, 4 independent pair-groups)
    lstm_persistent<<<256, 512, 0, stream>>>(
        U16(o_w1), U16(o_w2), U16(o_w3), U16(o_wsm),
        cond, dmask, bih1, bhh1, bih2, bhh2,
        F32(o_c1), F32(o_c2),
        U16(o_h1h), U16(o_h1l), U16(o_h2h), U16(o_h2l),
        Wfc, bfc, out, (unsigned*)(wsb + o_bar));
}